// Round 10
// baseline (303.099 us; speedup 1.0000x reference)
//
#include <hip/hip_runtime.h>
#include <hip/hip_bf16.h>
#include <math.h>

// GraphSAGE 3-layer, mean aggr, bf16 + MFMA. Round 10: occupancy/MLP bumps.
//  - bin: 1024 blocks (was 512; occupancy 14.7% -> predict ~29%)
//  - prep: bcount segment 512 blocks (was 256)
//  - bsort: 512 threads/block (was 256)
//  - agg64/agg40lsm: gather unroll 8 (was 4) for deeper MLP
// Structure otherwise identical to r9 (proven 285us).

#define BK_SHIFT 7
#define BK_NODES 128
#define NB_MAX   1024

typedef __attribute__((ext_vector_type(8))) short short8;
typedef __attribute__((ext_vector_type(4))) float f32x4;

__device__ inline float blo(unsigned v) { union { unsigned u; float f; } c; c.u = v << 16; return c.f; }
__device__ inline float bhi(unsigned v) { union { unsigned u; float f; } c; c.u = v & 0xFFFF0000u; return c.f; }
__device__ inline unsigned short f2bf(float f) {
    union { float f; unsigned u; } c; c.f = f;
    unsigned r = (c.u + 0x7FFFu + ((c.u >> 16) & 1u)) >> 16;
    return (unsigned short)r;
}

// ---------------- prep: bcount (blocks 0..511) + wconv (512..599) + xconv (600..1623) ----------------
__global__ __launch_bounds__(256) void prep_kernel(const int* __restrict__ dstA, int* __restrict__ bcount,
                                                   int E, int NB,
                                                   const float* __restrict__ x, unsigned short* __restrict__ Xb, int n8,
                                                   const float* __restrict__ Wl1, const float* __restrict__ Wr1,
                                                   const float* __restrict__ Wl2, const float* __restrict__ Wr2,
                                                   const float* __restrict__ Wl3, const float* __restrict__ Wr3,
                                                   unsigned short* __restrict__ Wb1,
                                                   unsigned short* __restrict__ Wb2,
                                                   unsigned short* __restrict__ Wb3) {
    int b = blockIdx.x, t = threadIdx.x;
    if (b < 512) {
        __shared__ int lc[NB_MAX];
        for (int i = t; i < NB; i += 256) lc[i] = 0;
        __syncthreads();
        for (int e = b * 256 + t; e < E; e += 512 * 256)
            atomicAdd(&lc[dstA[e] >> BK_SHIFT], 1);
        __syncthreads();
        for (int i = t; i < NB; i += 256)
            if (lc[i]) atomicAdd(&bcount[i], lc[i]);
    } else if (b < 600) {
        int i = (b - 512) * 256 + t;     // 88*256 = 22528 tasks
        if (i < 8192) {
            int c = i >> 7, k = i & 127;
            float v = (k < 64) ? Wl1[c * 64 + k] : Wr1[c * 64 + k - 64];
            Wb1[i] = f2bf(v);
        } else if (i < 16384) {
            int j = i - 8192;
            int c = j >> 7, k = j & 127;
            float v = (k < 64) ? Wl2[c * 64 + k] : Wr2[c * 64 + k - 64];
            Wb2[j] = f2bf(v);
        } else if (i < 22528) {
            int j = i - 16384;
            int c = j >> 6, k = j & 63;
            float v = 0.f;
            if (c < 40) v = Wl3[c * 64 + k];
            else if (c >= 48 && c < 88) v = Wr3[(c - 48) * 64 + k];
            Wb3[j] = f2bf(v);
        }
    } else {
        for (int i = (b - 600) * 256 + t; i < n8; i += 1024 * 256) {
            const float* p = x + (size_t)i * 8;
            float4 a = *(const float4*)p;
            float4 bq = *(const float4*)(p + 4);
            uint4 o;
            o.x = f2bf(a.x) | ((unsigned)f2bf(a.y) << 16);
            o.y = f2bf(a.z) | ((unsigned)f2bf(a.w) << 16);
            o.z = f2bf(bq.x) | ((unsigned)f2bf(bq.y) << 16);
            o.w = f2bf(bq.z) | ((unsigned)f2bf(bq.w) << 16);
            *(uint4*)(Xb + (size_t)i * 8) = o;
        }
    }
}

// ---------------- scan bucket counts ----------------
__global__ __launch_bounds__(1024) void bscan_kernel(const int* __restrict__ bcount,
                                                     int* __restrict__ bbase,
                                                     int* __restrict__ cursor, int NB, int E) {
    __shared__ int s[1024];
    int t = threadIdx.x;
    int v = (t < NB) ? bcount[t] : 0;
    s[t] = v;
    __syncthreads();
    for (int off = 1; off < 1024; off <<= 1) {
        int x = 0;
        if (t >= off) x = s[t - off];
        __syncthreads();
        s[t] += x;
        __syncthreads();
    }
    if (t < NB) {
        int ex = s[t] - v;
        bbase[t] = ex;
        cursor[t] = ex;
    }
    if (t == 0) bbase[NB] = E;
}

// ---------------- bin edges (src | dstLocal<<24) ----------------
__global__ __launch_bounds__(256) void bin_kernel(const int* __restrict__ srcA,
                                                  const int* __restrict__ dstA,
                                                  int* __restrict__ cursor,
                                                  int* __restrict__ binned, int E, int NB) {
    __shared__ int lc[NB_MAX];
    __shared__ int lbase[NB_MAX];
    int t = threadIdx.x;
    int chunk = (E + gridDim.x - 1) / gridDim.x;
    int e0 = blockIdx.x * chunk;
    int e1 = min(E, e0 + chunk);
    for (int i = t; i < NB; i += 256) lc[i] = 0;
    __syncthreads();
    for (int e = e0 + t; e < e1; e += 256)
        atomicAdd(&lc[dstA[e] >> BK_SHIFT], 1);
    __syncthreads();
    for (int i = t; i < NB; i += 256) {
        int c = lc[i];
        lbase[i] = c ? atomicAdd(&cursor[i], c) : 0;
    }
    __syncthreads();
    for (int i = t; i < NB; i += 256) lc[i] = 0;
    __syncthreads();
    for (int e = e0 + t; e < e1; e += 256) {
        int d = dstA[e];
        int b = d >> BK_SHIFT;
        int r = atomicAdd(&lc[b], 1);
        binned[lbase[b] + r] = srcA[e] | ((d & (BK_NODES - 1)) << 24);
    }
}

// ---------------- per-bucket counting sort -> sorted CSR (512 threads) ----------------
__global__ __launch_bounds__(512) void bsort_kernel(const int* __restrict__ binned,
                                                    const int* __restrict__ bbase,
                                                    int* __restrict__ col,
                                                    int* __restrict__ row_start, int N) {
    __shared__ int cnt[BK_NODES];
    __shared__ int base[BK_NODES];
    __shared__ int s[BK_NODES];
    int b = blockIdx.x, t = threadIdx.x;
    int e0 = bbase[b], e1 = bbase[b + 1];
    if (t < BK_NODES) cnt[t] = 0;
    __syncthreads();
    for (int e = e0 + t; e < e1; e += 512)
        atomicAdd(&cnt[(unsigned)binned[e] >> 24], 1);
    __syncthreads();
    int v = (t < BK_NODES) ? cnt[t] : 0;
    if (t < BK_NODES) s[t] = v;
    __syncthreads();
    for (int off = 1; off < BK_NODES; off <<= 1) {
        int x = 0;
        if (t < BK_NODES && t >= off) x = s[t - off];
        __syncthreads();
        if (t < BK_NODES) s[t] += x;
        __syncthreads();
    }
    if (t < BK_NODES) {
        base[t] = e0 + s[t] - v;
        int node = b * BK_NODES + t;
        if (node < N) row_start[node] = base[t];
        cnt[t] = 0;
    }
    if (b == gridDim.x - 1 && t == 0) row_start[N] = e1;
    __syncthreads();
    for (int e = e0 + t; e < e1; e += 512) {
        unsigned p = (unsigned)binned[e];
        int dl = p >> 24;
        int pos = base[dl] + atomicAdd(&cnt[dl], 1);
        col[pos] = p & 0xFFFFFF;
    }
}

// ---------------- mean aggregation, 64 bf16 dims: 8-lane group/node, uint4, unroll 8 ----------------
__global__ __launch_bounds__(256) void agg64_kernel(const unsigned short* __restrict__ X,
                                                    const int* __restrict__ rs,
                                                    const int* __restrict__ col,
                                                    unsigned short* __restrict__ OUT, int n) {
    int t = threadIdx.x;
    int node = blockIdx.x * 32 + (t >> 3);
    if (node >= n) return;
    int lane = t & 7;
    int s = rs[node], d = rs[node + 1] - s;
    const unsigned short* lp = X + lane * 8;
    float a0 = 0.f, a1 = 0.f, a2 = 0.f, a3 = 0.f, a4 = 0.f, a5 = 0.f, a6 = 0.f, a7 = 0.f;
    int j = 0;
    for (; j + 7 < d; j += 8) {
        uint4 q0 = *(const uint4*)(lp + (size_t)col[s + j + 0] * 64);
        uint4 q1 = *(const uint4*)(lp + (size_t)col[s + j + 1] * 64);
        uint4 q2 = *(const uint4*)(lp + (size_t)col[s + j + 2] * 64);
        uint4 q3 = *(const uint4*)(lp + (size_t)col[s + j + 3] * 64);
        uint4 q4 = *(const uint4*)(lp + (size_t)col[s + j + 4] * 64);
        uint4 q5 = *(const uint4*)(lp + (size_t)col[s + j + 5] * 64);
        uint4 q6 = *(const uint4*)(lp + (size_t)col[s + j + 6] * 64);
        uint4 q7 = *(const uint4*)(lp + (size_t)col[s + j + 7] * 64);
        a0 += ((blo(q0.x) + blo(q1.x)) + (blo(q2.x) + blo(q3.x))) + ((blo(q4.x) + blo(q5.x)) + (blo(q6.x) + blo(q7.x)));
        a1 += ((bhi(q0.x) + bhi(q1.x)) + (bhi(q2.x) + bhi(q3.x))) + ((bhi(q4.x) + bhi(q5.x)) + (bhi(q6.x) + bhi(q7.x)));
        a2 += ((blo(q0.y) + blo(q1.y)) + (blo(q2.y) + blo(q3.y))) + ((blo(q4.y) + blo(q5.y)) + (blo(q6.y) + blo(q7.y)));
        a3 += ((bhi(q0.y) + bhi(q1.y)) + (bhi(q2.y) + bhi(q3.y))) + ((bhi(q4.y) + bhi(q5.y)) + (bhi(q6.y) + bhi(q7.y)));
        a4 += ((blo(q0.z) + blo(q1.z)) + (blo(q2.z) + blo(q3.z))) + ((blo(q4.z) + blo(q5.z)) + (blo(q6.z) + blo(q7.z)));
        a5 += ((bhi(q0.z) + bhi(q1.z)) + (bhi(q2.z) + bhi(q3.z))) + ((bhi(q4.z) + bhi(q5.z)) + (bhi(q6.z) + bhi(q7.z)));
        a6 += ((blo(q0.w) + blo(q1.w)) + (blo(q2.w) + blo(q3.w))) + ((blo(q4.w) + blo(q5.w)) + (blo(q6.w) + blo(q7.w)));
        a7 += ((bhi(q0.w) + bhi(q1.w)) + (bhi(q2.w) + bhi(q3.w))) + ((bhi(q4.w) + bhi(q5.w)) + (bhi(q6.w) + bhi(q7.w)));
    }
    for (; j + 3 < d; j += 4) {
        uint4 q0 = *(const uint4*)(lp + (size_t)col[s + j + 0] * 64);
        uint4 q1 = *(const uint4*)(lp + (size_t)col[s + j + 1] * 64);
        uint4 q2 = *(const uint4*)(lp + (size_t)col[s + j + 2] * 64);
        uint4 q3 = *(const uint4*)(lp + (size_t)col[s + j + 3] * 64);
        a0 += (blo(q0.x) + blo(q1.x)) + (blo(q2.x) + blo(q3.x));
        a1 += (bhi(q0.x) + bhi(q1.x)) + (bhi(q2.x) + bhi(q3.x));
        a2 += (blo(q0.y) + blo(q1.y)) + (blo(q2.y) + blo(q3.y));
        a3 += (bhi(q0.y) + bhi(q1.y)) + (bhi(q2.y) + bhi(q3.y));
        a4 += (blo(q0.z) + blo(q1.z)) + (blo(q2.z) + blo(q3.z));
        a5 += (bhi(q0.z) + bhi(q1.z)) + (bhi(q2.z) + bhi(q3.z));
        a6 += (blo(q0.w) + blo(q1.w)) + (blo(q2.w) + blo(q3.w));
        a7 += (bhi(q0.w) + bhi(q1.w)) + (bhi(q2.w) + bhi(q3.w));
    }
    for (; j < d; ++j) {
        uint4 q0 = *(const uint4*)(lp + (size_t)col[s + j] * 64);
        a0 += blo(q0.x); a1 += bhi(q0.x); a2 += blo(q0.y); a3 += bhi(q0.y);
        a4 += blo(q0.z); a5 += bhi(q0.z); a6 += blo(q0.w); a7 += bhi(q0.w);
    }
    float w = 1.f / (float)(d > 0 ? d : 1);
    a0 *= w; a1 *= w; a2 *= w; a3 *= w; a4 *= w; a5 *= w; a6 *= w; a7 *= w;
    uint4 o;
    o.x = f2bf(a0) | ((unsigned)f2bf(a1) << 16);
    o.y = f2bf(a2) | ((unsigned)f2bf(a3) << 16);
    o.z = f2bf(a4) | ((unsigned)f2bf(a5) << 16);
    o.w = f2bf(a6) | ((unsigned)f2bf(a7) << 16);
    *(uint4*)(OUT + (size_t)node * 64 + lane * 8) = o;
}

// ---------------- MFMA linear 1/2: OUT = relu([A|X]@Wb^T + b), K=128 ----------------
__global__ __launch_bounds__(256) void linmfma12_kernel(const unsigned short* __restrict__ A,
                                                        const unsigned short* __restrict__ X,
                                                        const unsigned short* __restrict__ Wb,
                                                        const float* __restrict__ bias,
                                                        unsigned short* __restrict__ OUT,
                                                        int N) {
    __shared__ unsigned short Ys[64][136];
    __shared__ unsigned short Ws[64][136];
    int t = threadIdx.x;
    int rowbase = blockIdx.x * 64;
#pragma unroll
    for (int it = 0; it < 4; ++it) {
        int idx = it * 256 + t;
        int row = idx >> 4, c = idx & 15;
        int grow = rowbase + row;
        if (grow >= N) grow = N - 1;
        const unsigned short* src = (c < 8) ? (A + (size_t)grow * 64 + c * 8)
                                            : (X + (size_t)grow * 64 + (c - 8) * 8);
        *(short8*)&Ys[row][c * 8] = *(const short8*)src;
        *(short8*)&Ws[row][c * 8] = *(const short8*)(Wb + (size_t)row * 128 + c * 8);
    }
    __syncthreads();
    int l = t & 63, w = t >> 6;
    int lrow = l & 15, lk = l >> 4;
    f32x4 acc0 = {0.f, 0.f, 0.f, 0.f};
    f32x4 acc1 = acc0, acc2 = acc0, acc3 = acc0;
#pragma unroll
    for (int kk = 0; kk < 4; ++kk) {
        int ko = kk * 32 + lk * 8;
        short8 a  = *(const short8*)&Ys[16 * w + lrow][ko];
        short8 b0 = *(const short8*)&Ws[lrow][ko];
        short8 b1 = *(const short8*)&Ws[16 + lrow][ko];
        short8 b2 = *(const short8*)&Ws[32 + lrow][ko];
        short8 b3 = *(const short8*)&Ws[48 + lrow][ko];
        acc0 = __builtin_amdgcn_mfma_f32_16x16x32_bf16(a, b0, acc0, 0, 0, 0);
        acc1 = __builtin_amdgcn_mfma_f32_16x16x32_bf16(a, b1, acc1, 0, 0, 0);
        acc2 = __builtin_amdgcn_mfma_f32_16x16x32_bf16(a, b2, acc2, 0, 0, 0);
        acc3 = __builtin_amdgcn_mfma_f32_16x16x32_bf16(a, b3, acc3, 0, 0, 0);
    }
#define EPI12(nt, accv)                                                   \
    {                                                                     \
        int colc = 16 * (nt) + lrow;                                      \
        float bv = bias[colc];                                            \
        _Pragma("unroll") for (int i = 0; i < 4; ++i) {                   \
            int grow = rowbase + 16 * w + lk * 4 + i;                     \
            if (grow < N) {                                               \
                float v = fmaxf(accv[i] + bv, 0.f);                       \
                OUT[(size_t)grow * 64 + colc] = f2bf(v);                  \
            }                                                             \
        }                                                                 \
    }
    EPI12(0, acc0) EPI12(1, acc1) EPI12(2, acc2) EPI12(3, acc3)
#undef EPI12
}

// ---------------- MFMA linear 3: Z = h2@Wl3^T (bf16), R = h2@Wr3^T + b3 (fp32) ----------------
__global__ __launch_bounds__(256) void linmfma3_kernel(const unsigned short* __restrict__ H,
                                                       const unsigned short* __restrict__ Wb3,
                                                       const float* __restrict__ b3,
                                                       unsigned short* __restrict__ Z,
                                                       float* __restrict__ R,
                                                       int N) {
    __shared__ unsigned short Ys[64][72];
    __shared__ unsigned short Ws[96][72];
    int t = threadIdx.x;
    int rowbase = blockIdx.x * 64;
#pragma unroll
    for (int it = 0; it < 2; ++it) {
        int idx = it * 256 + t;
        int row = idx >> 3, c = idx & 7;
        int grow = rowbase + row;
        if (grow >= N) grow = N - 1;
        *(short8*)&Ys[row][c * 8] = *(const short8*)(H + (size_t)grow * 64 + c * 8);
    }
#pragma unroll
    for (int it = 0; it < 3; ++it) {
        int idx = it * 256 + t;
        int row = idx >> 3, c = idx & 7;
        *(short8*)&Ws[row][c * 8] = *(const short8*)(Wb3 + (size_t)row * 64 + c * 8);
    }
    __syncthreads();
    int l = t & 63, w = t >> 6;
    int lrow = l & 15, lk = l >> 4;
    f32x4 acc0 = {0.f, 0.f, 0.f, 0.f};
    f32x4 acc1 = acc0, acc2 = acc0, acc3 = acc0, acc4 = acc0, acc5 = acc0;
#pragma unroll
    for (int kk = 0; kk < 2; ++kk) {
        int ko = kk * 32 + lk * 8;
        short8 a  = *(const short8*)&Ys[16 * w + lrow][ko];
        short8 b0 = *(const short8*)&Ws[lrow][ko];
        short8 b1 = *(const short8*)&Ws[16 + lrow][ko];
        short8 b2 = *(const short8*)&Ws[32 + lrow][ko];
        short8 b3f = *(const short8*)&Ws[48 + lrow][ko];
        short8 b4 = *(const short8*)&Ws[64 + lrow][ko];
        short8 b5 = *(const short8*)&Ws[80 + lrow][ko];
        acc0 = __builtin_amdgcn_mfma_f32_16x16x32_bf16(a, b0, acc0, 0, 0, 0);
        acc1 = __builtin_amdgcn_mfma_f32_16x16x32_bf16(a, b1, acc1, 0, 0, 0);
        acc2 = __builtin_amdgcn_mfma_f32_16x16x32_bf16(a, b2, acc2, 0, 0, 0);
        acc3 = __builtin_amdgcn_mfma_f32_16x16x32_bf16(a, b3f, acc3, 0, 0, 0);
        acc4 = __builtin_amdgcn_mfma_f32_16x16x32_bf16(a, b4, acc4, 0, 0, 0);
        acc5 = __builtin_amdgcn_mfma_f32_16x16x32_bf16(a, b5, acc5, 0, 0, 0);
    }
#define EPI3(nt, accv)                                                     \
    {                                                                      \
        int colc = 16 * (nt) + lrow;                                       \
        _Pragma("unroll") for (int i = 0; i < 4; ++i) {                    \
            int grow = rowbase + 16 * w + lk * 4 + i;                      \
            if (grow < N) {                                                \
                float v = accv[i];                                         \
                if (colc < 40) {                                           \
                    Z[(size_t)grow * 40 + colc] = f2bf(v);                 \
                } else if (colc >= 48 && colc < 88) {                      \
                    R[(size_t)grow * 40 + (colc - 48)] = v + b3[colc - 48];\
                }                                                          \
            }                                                              \
        }                                                                  \
    }
    EPI3(0, acc0) EPI3(1, acc1) EPI3(2, acc2) EPI3(3, acc3) EPI3(4, acc4) EPI3(5, acc5)
#undef EPI3
}

// ---------------- agg(40 bf16) + self add + fused log_softmax: 8-lane group/node, unroll 8 ----------------
__global__ __launch_bounds__(256) void agg40lsm_kernel(const unsigned short* __restrict__ Z,
                                                       const int* __restrict__ rs,
                                                       const int* __restrict__ col,
                                                       float* __restrict__ out, int n) {
    int t = threadIdx.x;
    int node = blockIdx.x * 32 + (t >> 3);
    if (node >= n) return;
    int lane = t & 7;
    bool act = lane < 5;
    int s = rs[node], d = rs[node + 1] - s;
    const unsigned short* lp = Z + lane * 8;
    float a0 = 0.f, a1 = 0.f, a2 = 0.f, a3 = 0.f, a4 = 0.f, a5 = 0.f, a6 = 0.f, a7 = 0.f;
    int j = 0;
    for (; j + 7 < d; j += 8) {
        if (act) {
            uint4 q0 = *(const uint4*)(lp + (size_t)col[s + j + 0] * 40);
            uint4 q1 = *(const uint4*)(lp + (size_t)col[s + j + 1] * 40);
            uint4 q2 = *(const uint4*)(lp + (size_t)col[s + j + 2] * 40);
            uint4 q3 = *(const uint4*)(lp + (size_t)col[s + j + 3] * 40);
            uint4 q4 = *(const uint4*)(lp + (size_t)col[s + j + 4] * 40);
            uint4 q5 = *(const uint4*)(lp + (size_t)col[s + j + 5] * 40);
            uint4 q6 = *(const uint4*)(lp + (size_t)col[s + j + 6] * 40);
            uint4 q7 = *(const uint4*)(lp + (size_t)col[s + j + 7] * 40);
            a0 += ((blo(q0.x) + blo(q1.x)) + (blo(q2.x) + blo(q3.x))) + ((blo(q4.x) + blo(q5.x)) + (blo(q6.x) + blo(q7.x)));
            a1 += ((bhi(q0.x) + bhi(q1.x)) + (bhi(q2.x) + bhi(q3.x))) + ((bhi(q4.x) + bhi(q5.x)) + (bhi(q6.x) + bhi(q7.x)));
            a2 += ((blo(q0.y) + blo(q1.y)) + (blo(q2.y) + blo(q3.y))) + ((blo(q4.y) + blo(q5.y)) + (blo(q6.y) + blo(q7.y)));
            a3 += ((bhi(q0.y) + bhi(q1.y)) + (bhi(q2.y) + bhi(q3.y))) + ((bhi(q4.y) + bhi(q5.y)) + (bhi(q6.y) + bhi(q7.y)));
            a4 += ((blo(q0.z) + blo(q1.z)) + (blo(q2.z) + blo(q3.z))) + ((blo(q4.z) + blo(q5.z)) + (blo(q6.z) + blo(q7.z)));
            a5 += ((bhi(q0.z) + bhi(q1.z)) + (bhi(q2.z) + bhi(q3.z))) + ((bhi(q4.z) + bhi(q5.z)) + (bhi(q6.z) + bhi(q7.z)));
            a6 += ((blo(q0.w) + blo(q1.w)) + (blo(q2.w) + blo(q3.w))) + ((blo(q4.w) + blo(q5.w)) + (blo(q6.w) + blo(q7.w)));
            a7 += ((bhi(q0.w) + bhi(q1.w)) + (bhi(q2.w) + bhi(q3.w))) + ((bhi(q4.w) + bhi(q5.w)) + (bhi(q6.w) + bhi(q7.w)));
        }
    }
    for (; j < d; ++j) {
        if (act) {
            uint4 q0 = *(const uint4*)(lp + (size_t)col[s + j] * 40);
            a0 += blo(q0.x); a1 += bhi(q0.x); a2 += blo(q0.y); a3 += bhi(q0.y);
            a4 += blo(q0.z); a5 += bhi(q0.z); a6 += blo(q0.w); a7 += bhi(q0.w);
        }
    }
    float w = 1.f / (float)(d > 0 ? d : 1);
    if (act) {
        float* op = out + (size_t)node * 40 + lane * 8;
        float4 r0 = *(const float4*)op;
        float4 r1 = *(const float4*)(op + 4);
        a0 = a0 * w + r0.x; a1 = a1 * w + r0.y; a2 = a2 * w + r0.z; a3 = a3 * w + r0.w;
        a4 = a4 * w + r1.x; a5 = a5 * w + r1.y; a6 = a6 * w + r1.z; a7 = a7 * w + r1.w;
    }
    float mx = act ? fmaxf(fmaxf(fmaxf(a0, a1), fmaxf(a2, a3)),
                           fmaxf(fmaxf(a4, a5), fmaxf(a6, a7))) : -3.4e38f;
#pragma unroll
    for (int off = 1; off < 8; off <<= 1) mx = fmaxf(mx, __shfl_xor(mx, off, 8));
    float ssum = act ? (expf(a0 - mx) + expf(a1 - mx) + expf(a2 - mx) + expf(a3 - mx) +
                        expf(a4 - mx) + expf(a5 - mx) + expf(a6 - mx) + expf(a7 - mx)) : 0.f;
#pragma unroll
    for (int off = 1; off < 8; off <<= 1) ssum += __shfl_xor(ssum, off, 8);
    float lg = mx + logf(ssum);
    if (act) {
        float* op = out + (size_t)node * 40 + lane * 8;
        float4 o0, o1;
        o0.x = a0 - lg; o0.y = a1 - lg; o0.z = a2 - lg; o0.w = a3 - lg;
        o1.x = a4 - lg; o1.y = a5 - lg; o1.z = a6 - lg; o1.w = a7 - lg;
        *(float4*)op = o0;
        *(float4*)(op + 4) = o1;
    }
}

// ---------------- launch ----------------
extern "C" void kernel_launch(void* const* d_in, const int* in_sizes, int n_in,
                              void* d_out, int out_size, void* d_ws, size_t ws_size,
                              hipStream_t stream) {
    const float* x   = (const float*)d_in[0];
    const int*   ei  = (const int*)d_in[1];
    const float* Wl1 = (const float*)d_in[2];
    const float* Wr1 = (const float*)d_in[3];
    const float* b1  = (const float*)d_in[4];
    const float* Wl2 = (const float*)d_in[5];
    const float* Wr2 = (const float*)d_in[6];
    const float* b2  = (const float*)d_in[7];
    const float* Wl3 = (const float*)d_in[8];
    const float* Wr3 = (const float*)d_in[9];
    const float* b3  = (const float*)d_in[10];
    float* out = (float*)d_out;

    const int N = in_sizes[0] / 64;
    const int E = in_sizes[1] / 2;
    const int NB = (N + BK_NODES - 1) / BK_NODES;
    const int* srcA = ei;
    const int* dstA = ei + E;

    char* ws = (char*)d_ws;
    size_t off = 0;
    auto alloc = [&](size_t bytes) {
        off = (off + 255) & ~(size_t)255;
        char* p = ws + off;
        off += bytes;
        return p;
    };
    int* bcount    = (int*)alloc((size_t)(NB_MAX + 1) * 4);
    int* bbase     = (int*)alloc((size_t)(NB_MAX + 1) * 4);
    int* cursor    = (int*)alloc((size_t)NB_MAX * 4);
    int* binned    = (int*)alloc((size_t)E * 4);
    int* col       = (int*)alloc((size_t)E * 4);
    int* row_start = (int*)alloc((size_t)(N + 1) * 4);
    unsigned short* Xb  = (unsigned short*)alloc((size_t)N * 64 * 2);
    unsigned short* AGG = (unsigned short*)alloc((size_t)N * 64 * 2);
    unsigned short* Hb  = (unsigned short*)alloc((size_t)N * 64 * 2);
    unsigned short* Zb  = (unsigned short*)alloc((size_t)N * 40 * 2);
    unsigned short* Wb1 = (unsigned short*)alloc(8192 * 2);
    unsigned short* Wb2 = (unsigned short*)alloc(8192 * 2);
    unsigned short* Wb3 = (unsigned short*)alloc(6144 * 2);

    // build sorted CSR via dst-buckets (+ fused dtype conversions)
    hipMemsetAsync(bcount, 0, (size_t)(NB + 1) * 4, stream);
    prep_kernel<<<1624, 256, 0, stream>>>(dstA, bcount, E, NB, x, Xb, N * 64 / 8,
                                          Wl1, Wr1, Wl2, Wr2, Wl3, Wr3, Wb1, Wb2, Wb3);
    bscan_kernel<<<1, 1024, 0, stream>>>(bcount, bbase, cursor, NB, E);
    bin_kernel<<<1024, 256, 0, stream>>>(srcA, dstA, cursor, binned, E, NB);
    bsort_kernel<<<NB, 512, 0, stream>>>(binned, bbase, col, row_start, N);

    int gridA = (N + 31) / 32;
    int gridM = (N + 63) / 64;

    // layer 1
    agg64_kernel<<<gridA, 256, 0, stream>>>(Xb, row_start, col, AGG, N);
    linmfma12_kernel<<<gridM, 256, 0, stream>>>(AGG, Xb, Wb1, b1, Hb, N);

    // layer 2 (lin in-place on Hb: each block stages its own rows before writing)
    agg64_kernel<<<gridA, 256, 0, stream>>>(Hb, row_start, col, AGG, N);
    linmfma12_kernel<<<gridM, 256, 0, stream>>>(AGG, Hb, Wb2, b2, Hb, N);

    // layer 3: pre-transform (agg is linear), then agg(40) + self + log_softmax
    linmfma3_kernel<<<gridM, 256, 0, stream>>>(Hb, Wb3, b3, Zb, out, N);
    agg40lsm_kernel<<<gridA, 256, 0, stream>>>(Zb, row_start, col, out, N);
}

// Round 12
// 264.134 us; speedup vs baseline: 1.1475x; 1.1475x over previous
//
#include <hip/hip_runtime.h>
#include <hip/hip_bf16.h>
#include <math.h>

// GraphSAGE 3-layer, mean aggr, bf16 + MFMA. Round 11 (resubmit after broker
// timeout): deterministic binning.
// r10 post-mortem: bin@1024 regressed (global cursor atomic chains + 6B write
// runs). New scheme: prep counts exact per-(block,bucket) rows (no atomics) ->
// colscan (per-bucket prefix over blocks) -> bscan (bucket bases) -> bin is
// SINGLE-pass with LDS-only cursors (zero global atomics), 256 blocks x 512 thr
// (32B write runs, 8 waves/CU). All else = r9 (proven 285us).

#define BK_SHIFT 7
#define BK_NODES 128
#define NB_MAX   1024
#define BBLK     256      // bin blocks (rows of cnts)

typedef __attribute__((ext_vector_type(8))) short short8;
typedef __attribute__((ext_vector_type(4))) float f32x4;

__device__ inline float blo(unsigned v) { union { unsigned u; float f; } c; c.u = v << 16; return c.f; }
__device__ inline float bhi(unsigned v) { union { unsigned u; float f; } c; c.u = v & 0xFFFF0000u; return c.f; }
__device__ inline unsigned short f2bf(float f) {
    union { float f; unsigned u; } c; c.f = f;
    unsigned r = (c.u + 0x7FFFu + ((c.u >> 16) & 1u)) >> 16;
    return (unsigned short)r;
}

// ---------------- prep: per-block bucket counts (0..255) + wconv (256..343) + xconv (344..1367) ----------------
__global__ __launch_bounds__(256) void prep_kernel(const int* __restrict__ dstA, int* __restrict__ cnts,
                                                   int E, int NB,
                                                   const float* __restrict__ x, unsigned short* __restrict__ Xb, int n8,
                                                   const float* __restrict__ Wl1, const float* __restrict__ Wr1,
                                                   const float* __restrict__ Wl2, const float* __restrict__ Wr2,
                                                   const float* __restrict__ Wl3, const float* __restrict__ Wr3,
                                                   unsigned short* __restrict__ Wb1,
                                                   unsigned short* __restrict__ Wb2,
                                                   unsigned short* __restrict__ Wb3) {
    int b = blockIdx.x, t = threadIdx.x;
    if (b < BBLK) {
        // exact count of this block's bin-chunk (chunk mapping MUST match bin_kernel)
        __shared__ int lc[NB_MAX];
        for (int i = t; i < NB_MAX; i += 256) lc[i] = 0;
        __syncthreads();
        int chunk = (E + BBLK - 1) / BBLK;
        int e0 = b * chunk, e1 = min(E, e0 + chunk);
        for (int e = e0 + t; e < e1; e += 256)
            atomicAdd(&lc[dstA[e] >> BK_SHIFT], 1);
        __syncthreads();
        for (int i = t; i < NB_MAX; i += 256) cnts[b * NB_MAX + i] = lc[i];
    } else if (b < BBLK + 88) {
        int i = (b - BBLK) * 256 + t;     // 88*256 = 22528 tasks
        if (i < 8192) {
            int c = i >> 7, k = i & 127;
            float v = (k < 64) ? Wl1[c * 64 + k] : Wr1[c * 64 + k - 64];
            Wb1[i] = f2bf(v);
        } else if (i < 16384) {
            int j = i - 8192;
            int c = j >> 7, k = j & 127;
            float v = (k < 64) ? Wl2[c * 64 + k] : Wr2[c * 64 + k - 64];
            Wb2[j] = f2bf(v);
        } else if (i < 22528) {
            int j = i - 16384;
            int c = j >> 6, k = j & 63;
            float v = 0.f;
            if (c < 40) v = Wl3[c * 64 + k];
            else if (c >= 48 && c < 88) v = Wr3[(c - 48) * 64 + k];
            Wb3[j] = f2bf(v);
        }
    } else {
        for (int i = (b - (BBLK + 88)) * 256 + t; i < n8; i += 1024 * 256) {
            const float* p = x + (size_t)i * 8;
            float4 a = *(const float4*)p;
            float4 bq = *(const float4*)(p + 4);
            uint4 o;
            o.x = f2bf(a.x) | ((unsigned)f2bf(a.y) << 16);
            o.y = f2bf(a.z) | ((unsigned)f2bf(a.w) << 16);
            o.z = f2bf(bq.x) | ((unsigned)f2bf(bq.y) << 16);
            o.w = f2bf(bq.z) | ((unsigned)f2bf(bq.w) << 16);
            *(uint4*)(Xb + (size_t)i * 8) = o;
        }
    }
}

// ---------------- colscan: per-bucket exclusive prefix over the 256 bin-blocks ----------------
// Block j handles bucket j: lpre[blk][j] = sum_{b'<blk} cnts[b'][j]; total -> bcount[j].
__global__ __launch_bounds__(256) void colscan_kernel(const int* __restrict__ cnts,
                                                      int* __restrict__ lpre,
                                                      int* __restrict__ bcount) {
    __shared__ int s[BBLK];
    int j = blockIdx.x, t = threadIdx.x;
    int v = cnts[t * NB_MAX + j];
    s[t] = v;
    __syncthreads();
    for (int off = 1; off < BBLK; off <<= 1) {
        int x = 0;
        if (t >= off) x = s[t - off];
        __syncthreads();
        s[t] += x;
        __syncthreads();
    }
    lpre[t * NB_MAX + j] = s[t] - v;      // exclusive
    if (t == BBLK - 1) bcount[j] = s[t];  // column total
}

// ---------------- scan bucket totals -> bbase ----------------
__global__ __launch_bounds__(1024) void bscan_kernel(const int* __restrict__ bcount,
                                                     int* __restrict__ bbase, int NB, int E) {
    __shared__ int s[1024];
    int t = threadIdx.x;
    int v = (t < NB) ? bcount[t] : 0;
    s[t] = v;
    __syncthreads();
    for (int off = 1; off < 1024; off <<= 1) {
        int x = 0;
        if (t >= off) x = s[t - off];
        __syncthreads();
        s[t] += x;
        __syncthreads();
    }
    if (t < NB) bbase[t] = s[t] - v;
    if (t == 0) bbase[NB] = E;
}

// ---------------- bin edges single-pass (src | dstLocal<<24), LDS cursors only ----------------
__global__ __launch_bounds__(512) void bin_kernel(const int* __restrict__ srcA,
                                                  const int* __restrict__ dstA,
                                                  const int* __restrict__ lpre,
                                                  const int* __restrict__ bbase,
                                                  int* __restrict__ binned, int E, int NB) {
    __shared__ int lc[NB_MAX];
    int b = blockIdx.x, t = threadIdx.x;
    for (int i = t; i < NB; i += 512)
        lc[i] = lpre[b * NB_MAX + i] + bbase[i];
    __syncthreads();
    int chunk = (E + BBLK - 1) / BBLK;
    int e0 = b * chunk, e1 = min(E, e0 + chunk);
    for (int e = e0 + t; e < e1; e += 512) {
        int d = dstA[e];
        int bk = d >> BK_SHIFT;
        int pos = atomicAdd(&lc[bk], 1);
        binned[pos] = srcA[e] | ((d & (BK_NODES - 1)) << 24);
    }
}

// ---------------- per-bucket counting sort -> sorted CSR ----------------
__global__ __launch_bounds__(256) void bsort_kernel(const int* __restrict__ binned,
                                                    const int* __restrict__ bbase,
                                                    int* __restrict__ col,
                                                    int* __restrict__ row_start, int N) {
    __shared__ int cnt[BK_NODES];
    __shared__ int base[BK_NODES];
    __shared__ int s[BK_NODES];
    int b = blockIdx.x, t = threadIdx.x;
    int e0 = bbase[b], e1 = bbase[b + 1];
    if (t < BK_NODES) cnt[t] = 0;
    __syncthreads();
    for (int e = e0 + t; e < e1; e += 256)
        atomicAdd(&cnt[(unsigned)binned[e] >> 24], 1);
    __syncthreads();
    int v = (t < BK_NODES) ? cnt[t] : 0;
    if (t < BK_NODES) s[t] = v;
    __syncthreads();
    for (int off = 1; off < BK_NODES; off <<= 1) {
        int x = 0;
        if (t < BK_NODES && t >= off) x = s[t - off];
        __syncthreads();
        if (t < BK_NODES) s[t] += x;
        __syncthreads();
    }
    if (t < BK_NODES) {
        base[t] = e0 + s[t] - v;
        int node = b * BK_NODES + t;
        if (node < N) row_start[node] = base[t];
        cnt[t] = 0;
    }
    if (b == gridDim.x - 1 && t == 0) row_start[N] = e1;
    __syncthreads();
    for (int e = e0 + t; e < e1; e += 256) {
        unsigned p = (unsigned)binned[e];
        int dl = p >> 24;
        int pos = base[dl] + atomicAdd(&cnt[dl], 1);
        col[pos] = p & 0xFFFFFF;
    }
}

// ---------------- mean aggregation, 64 bf16 dims: 8-lane group/node, uint4 ----------------
__global__ __launch_bounds__(256) void agg64_kernel(const unsigned short* __restrict__ X,
                                                    const int* __restrict__ rs,
                                                    const int* __restrict__ col,
                                                    unsigned short* __restrict__ OUT, int n) {
    int t = threadIdx.x;
    int node = blockIdx.x * 32 + (t >> 3);
    if (node >= n) return;
    int lane = t & 7;
    int s = rs[node], d = rs[node + 1] - s;
    const unsigned short* lp = X + lane * 8;
    float a0 = 0.f, a1 = 0.f, a2 = 0.f, a3 = 0.f, a4 = 0.f, a5 = 0.f, a6 = 0.f, a7 = 0.f;
    int j = 0;
    for (; j + 3 < d; j += 4) {
        int c0 = col[s + j], c1 = col[s + j + 1];
        int c2 = col[s + j + 2], c3 = col[s + j + 3];
        uint4 q0 = *(const uint4*)(lp + (size_t)c0 * 64);
        uint4 q1 = *(const uint4*)(lp + (size_t)c1 * 64);
        uint4 q2 = *(const uint4*)(lp + (size_t)c2 * 64);
        uint4 q3 = *(const uint4*)(lp + (size_t)c3 * 64);
        a0 += (blo(q0.x) + blo(q1.x)) + (blo(q2.x) + blo(q3.x));
        a1 += (bhi(q0.x) + bhi(q1.x)) + (bhi(q2.x) + bhi(q3.x));
        a2 += (blo(q0.y) + blo(q1.y)) + (blo(q2.y) + blo(q3.y));
        a3 += (bhi(q0.y) + bhi(q1.y)) + (bhi(q2.y) + bhi(q3.y));
        a4 += (blo(q0.z) + blo(q1.z)) + (blo(q2.z) + blo(q3.z));
        a5 += (bhi(q0.z) + bhi(q1.z)) + (bhi(q2.z) + bhi(q3.z));
        a6 += (blo(q0.w) + blo(q1.w)) + (blo(q2.w) + blo(q3.w));
        a7 += (bhi(q0.w) + bhi(q1.w)) + (bhi(q2.w) + bhi(q3.w));
    }
    for (; j < d; ++j) {
        int c0 = col[s + j];
        uint4 q0 = *(const uint4*)(lp + (size_t)c0 * 64);
        a0 += blo(q0.x); a1 += bhi(q0.x); a2 += blo(q0.y); a3 += bhi(q0.y);
        a4 += blo(q0.z); a5 += bhi(q0.z); a6 += blo(q0.w); a7 += bhi(q0.w);
    }
    float w = 1.f / (float)(d > 0 ? d : 1);
    a0 *= w; a1 *= w; a2 *= w; a3 *= w; a4 *= w; a5 *= w; a6 *= w; a7 *= w;
    uint4 o;
    o.x = f2bf(a0) | ((unsigned)f2bf(a1) << 16);
    o.y = f2bf(a2) | ((unsigned)f2bf(a3) << 16);
    o.z = f2bf(a4) | ((unsigned)f2bf(a5) << 16);
    o.w = f2bf(a6) | ((unsigned)f2bf(a7) << 16);
    *(uint4*)(OUT + (size_t)node * 64 + lane * 8) = o;
}

// ---------------- MFMA linear 1/2: OUT = relu([A|X]@Wb^T + b), K=128 ----------------
__global__ __launch_bounds__(256) void linmfma12_kernel(const unsigned short* __restrict__ A,
                                                        const unsigned short* __restrict__ X,
                                                        const unsigned short* __restrict__ Wb,
                                                        const float* __restrict__ bias,
                                                        unsigned short* __restrict__ OUT,
                                                        int N) {
    __shared__ unsigned short Ys[64][136];
    __shared__ unsigned short Ws[64][136];
    int t = threadIdx.x;
    int rowbase = blockIdx.x * 64;
#pragma unroll
    for (int it = 0; it < 4; ++it) {
        int idx = it * 256 + t;
        int row = idx >> 4, c = idx & 15;
        int grow = rowbase + row;
        if (grow >= N) grow = N - 1;
        const unsigned short* src = (c < 8) ? (A + (size_t)grow * 64 + c * 8)
                                            : (X + (size_t)grow * 64 + (c - 8) * 8);
        *(short8*)&Ys[row][c * 8] = *(const short8*)src;
        *(short8*)&Ws[row][c * 8] = *(const short8*)(Wb + (size_t)row * 128 + c * 8);
    }
    __syncthreads();
    int l = t & 63, w = t >> 6;
    int lrow = l & 15, lk = l >> 4;
    f32x4 acc0 = {0.f, 0.f, 0.f, 0.f};
    f32x4 acc1 = acc0, acc2 = acc0, acc3 = acc0;
#pragma unroll
    for (int kk = 0; kk < 4; ++kk) {
        int ko = kk * 32 + lk * 8;
        short8 a  = *(const short8*)&Ys[16 * w + lrow][ko];
        short8 b0 = *(const short8*)&Ws[lrow][ko];
        short8 b1 = *(const short8*)&Ws[16 + lrow][ko];
        short8 b2 = *(const short8*)&Ws[32 + lrow][ko];
        short8 b3 = *(const short8*)&Ws[48 + lrow][ko];
        acc0 = __builtin_amdgcn_mfma_f32_16x16x32_bf16(a, b0, acc0, 0, 0, 0);
        acc1 = __builtin_amdgcn_mfma_f32_16x16x32_bf16(a, b1, acc1, 0, 0, 0);
        acc2 = __builtin_amdgcn_mfma_f32_16x16x32_bf16(a, b2, acc2, 0, 0, 0);
        acc3 = __builtin_amdgcn_mfma_f32_16x16x32_bf16(a, b3, acc3, 0, 0, 0);
    }
#define EPI12(nt, accv)                                                   \
    {                                                                     \
        int colc = 16 * (nt) + lrow;                                      \
        float bv = bias[colc];                                            \
        _Pragma("unroll") for (int i = 0; i < 4; ++i) {                   \
            int grow = rowbase + 16 * w + lk * 4 + i;                     \
            if (grow < N) {                                               \
                float v = fmaxf(accv[i] + bv, 0.f);                       \
                OUT[(size_t)grow * 64 + colc] = f2bf(v);                  \
            }                                                             \
        }                                                                 \
    }
    EPI12(0, acc0) EPI12(1, acc1) EPI12(2, acc2) EPI12(3, acc3)
#undef EPI12
}

// ---------------- MFMA linear 3: Z = h2@Wl3^T (bf16), R = h2@Wr3^T + b3 (fp32) ----------------
__global__ __launch_bounds__(256) void linmfma3_kernel(const unsigned short* __restrict__ H,
                                                       const unsigned short* __restrict__ Wb3,
                                                       const float* __restrict__ b3,
                                                       unsigned short* __restrict__ Z,
                                                       float* __restrict__ R,
                                                       int N) {
    __shared__ unsigned short Ys[64][72];
    __shared__ unsigned short Ws[96][72];
    int t = threadIdx.x;
    int rowbase = blockIdx.x * 64;
#pragma unroll
    for (int it = 0; it < 2; ++it) {
        int idx = it * 256 + t;
        int row = idx >> 3, c = idx & 7;
        int grow = rowbase + row;
        if (grow >= N) grow = N - 1;
        *(short8*)&Ys[row][c * 8] = *(const short8*)(H + (size_t)grow * 64 + c * 8);
    }
#pragma unroll
    for (int it = 0; it < 3; ++it) {
        int idx = it * 256 + t;
        int row = idx >> 3, c = idx & 7;
        *(short8*)&Ws[row][c * 8] = *(const short8*)(Wb3 + (size_t)row * 64 + c * 8);
    }
    __syncthreads();
    int l = t & 63, w = t >> 6;
    int lrow = l & 15, lk = l >> 4;
    f32x4 acc0 = {0.f, 0.f, 0.f, 0.f};
    f32x4 acc1 = acc0, acc2 = acc0, acc3 = acc0, acc4 = acc0, acc5 = acc0;
#pragma unroll
    for (int kk = 0; kk < 2; ++kk) {
        int ko = kk * 32 + lk * 8;
        short8 a  = *(const short8*)&Ys[16 * w + lrow][ko];
        short8 b0 = *(const short8*)&Ws[lrow][ko];
        short8 b1 = *(const short8*)&Ws[16 + lrow][ko];
        short8 b2 = *(const short8*)&Ws[32 + lrow][ko];
        short8 b3f = *(const short8*)&Ws[48 + lrow][ko];
        short8 b4 = *(const short8*)&Ws[64 + lrow][ko];
        short8 b5 = *(const short8*)&Ws[80 + lrow][ko];
        acc0 = __builtin_amdgcn_mfma_f32_16x16x32_bf16(a, b0, acc0, 0, 0, 0);
        acc1 = __builtin_amdgcn_mfma_f32_16x16x32_bf16(a, b1, acc1, 0, 0, 0);
        acc2 = __builtin_amdgcn_mfma_f32_16x16x32_bf16(a, b2, acc2, 0, 0, 0);
        acc3 = __builtin_amdgcn_mfma_f32_16x16x32_bf16(a, b3f, acc3, 0, 0, 0);
        acc4 = __builtin_amdgcn_mfma_f32_16x16x32_bf16(a, b4, acc4, 0, 0, 0);
        acc5 = __builtin_amdgcn_mfma_f32_16x16x32_bf16(a, b5, acc5, 0, 0, 0);
    }
#define EPI3(nt, accv)                                                     \
    {                                                                      \
        int colc = 16 * (nt) + lrow;                                       \
        _Pragma("unroll") for (int i = 0; i < 4; ++i) {                    \
            int grow = rowbase + 16 * w + lk * 4 + i;                      \
            if (grow < N) {                                                \
                float v = accv[i];                                         \
                if (colc < 40) {                                           \
                    Z[(size_t)grow * 40 + colc] = f2bf(v);                 \
                } else if (colc >= 48 && colc < 88) {                      \
                    R[(size_t)grow * 40 + (colc - 48)] = v + b3[colc - 48];\
                }                                                          \
            }                                                              \
        }                                                                  \
    }
    EPI3(0, acc0) EPI3(1, acc1) EPI3(2, acc2) EPI3(3, acc3) EPI3(4, acc4) EPI3(5, acc5)
#undef EPI3
}

// ---------------- agg(40 bf16) + self add + fused log_softmax: 8-lane group/node ----------------
__global__ __launch_bounds__(256) void agg40lsm_kernel(const unsigned short* __restrict__ Z,
                                                       const int* __restrict__ rs,
                                                       const int* __restrict__ col,
                                                       float* __restrict__ out, int n) {
    int t = threadIdx.x;
    int node = blockIdx.x * 32 + (t >> 3);
    if (node >= n) return;
    int lane = t & 7;
    bool act = lane < 5;
    int s = rs[node], d = rs[node + 1] - s;
    const unsigned short* lp = Z + lane * 8;
    float a0 = 0.f, a1 = 0.f, a2 = 0.f, a3 = 0.f, a4 = 0.f, a5 = 0.f, a6 = 0.f, a7 = 0.f;
    int j = 0;
    for (; j + 3 < d; j += 4) {
        int c0 = col[s + j], c1 = col[s + j + 1];
        int c2 = col[s + j + 2], c3 = col[s + j + 3];
        if (act) {
            uint4 q0 = *(const uint4*)(lp + (size_t)c0 * 40);
            uint4 q1 = *(const uint4*)(lp + (size_t)c1 * 40);
            uint4 q2 = *(const uint4*)(lp + (size_t)c2 * 40);
            uint4 q3 = *(const uint4*)(lp + (size_t)c3 * 40);
            a0 += (blo(q0.x) + blo(q1.x)) + (blo(q2.x) + blo(q3.x));
            a1 += (bhi(q0.x) + bhi(q1.x)) + (bhi(q2.x) + bhi(q3.x));
            a2 += (blo(q0.y) + blo(q1.y)) + (blo(q2.y) + blo(q3.y));
            a3 += (bhi(q0.y) + bhi(q1.y)) + (bhi(q2.y) + bhi(q3.y));
            a4 += (blo(q0.z) + blo(q1.z)) + (blo(q2.z) + blo(q3.z));
            a5 += (bhi(q0.z) + bhi(q1.z)) + (bhi(q2.z) + bhi(q3.z));
            a6 += (blo(q0.w) + blo(q1.w)) + (blo(q2.w) + blo(q3.w));
            a7 += (bhi(q0.w) + bhi(q1.w)) + (bhi(q2.w) + bhi(q3.w));
        }
    }
    for (; j < d; ++j) {
        int c0 = col[s + j];
        if (act) {
            uint4 q0 = *(const uint4*)(lp + (size_t)c0 * 40);
            a0 += blo(q0.x); a1 += bhi(q0.x); a2 += blo(q0.y); a3 += bhi(q0.y);
            a4 += blo(q0.z); a5 += bhi(q0.z); a6 += blo(q0.w); a7 += bhi(q0.w);
        }
    }
    float w = 1.f / (float)(d > 0 ? d : 1);
    if (act) {
        float* op = out + (size_t)node * 40 + lane * 8;
        float4 r0 = *(const float4*)op;
        float4 r1 = *(const float4*)(op + 4);
        a0 = a0 * w + r0.x; a1 = a1 * w + r0.y; a2 = a2 * w + r0.z; a3 = a3 * w + r0.w;
        a4 = a4 * w + r1.x; a5 = a5 * w + r1.y; a6 = a6 * w + r1.z; a7 = a7 * w + r1.w;
    }
    float mx = act ? fmaxf(fmaxf(fmaxf(a0, a1), fmaxf(a2, a3)),
                           fmaxf(fmaxf(a4, a5), fmaxf(a6, a7))) : -3.4e38f;
#pragma unroll
    for (int off = 1; off < 8; off <<= 1) mx = fmaxf(mx, __shfl_xor(mx, off, 8));
    float ssum = act ? (expf(a0 - mx) + expf(a1 - mx) + expf(a2 - mx) + expf(a3 - mx) +
                        expf(a4 - mx) + expf(a5 - mx) + expf(a6 - mx) + expf(a7 - mx)) : 0.f;
#pragma unroll
    for (int off = 1; off < 8; off <<= 1) ssum += __shfl_xor(ssum, off, 8);
    float lg = mx + logf(ssum);
    if (act) {
        float* op = out + (size_t)node * 40 + lane * 8;
        float4 o0, o1;
        o0.x = a0 - lg; o0.y = a1 - lg; o0.z = a2 - lg; o0.w = a3 - lg;
        o1.x = a4 - lg; o1.y = a5 - lg; o1.z = a6 - lg; o1.w = a7 - lg;
        *(float4*)op = o0;
        *(float4*)(op + 4) = o1;
    }
}

// ---------------- launch ----------------
extern "C" void kernel_launch(void* const* d_in, const int* in_sizes, int n_in,
                              void* d_out, int out_size, void* d_ws, size_t ws_size,
                              hipStream_t stream) {
    const float* x   = (const float*)d_in[0];
    const int*   ei  = (const int*)d_in[1];
    const float* Wl1 = (const float*)d_in[2];
    const float* Wr1 = (const float*)d_in[3];
    const float* b1  = (const float*)d_in[4];
    const float* Wl2 = (const float*)d_in[5];
    const float* Wr2 = (const float*)d_in[6];
    const float* b2  = (const float*)d_in[7];
    const float* Wl3 = (const float*)d_in[8];
    const float* Wr3 = (const float*)d_in[9];
    const float* b3  = (const float*)d_in[10];
    float* out = (float*)d_out;

    const int N = in_sizes[0] / 64;
    const int E = in_sizes[1] / 2;
    const int NB = (N + BK_NODES - 1) / BK_NODES;
    const int* srcA = ei;
    const int* dstA = ei + E;

    char* ws = (char*)d_ws;
    size_t off = 0;
    auto alloc = [&](size_t bytes) {
        off = (off + 255) & ~(size_t)255;
        char* p = ws + off;
        off += bytes;
        return p;
    };
    int* cnts      = (int*)alloc((size_t)BBLK * NB_MAX * 4);
    int* lpre      = (int*)alloc((size_t)BBLK * NB_MAX * 4);
    int* bcount    = (int*)alloc((size_t)(NB_MAX + 1) * 4);
    int* bbase     = (int*)alloc((size_t)(NB_MAX + 1) * 4);
    int* binned    = (int*)alloc((size_t)E * 4);
    int* col       = (int*)alloc((size_t)E * 4);
    int* row_start = (int*)alloc((size_t)(N + 1) * 4);
    unsigned short* Xb  = (unsigned short*)alloc((size_t)N * 64 * 2);
    unsigned short* AGG = (unsigned short*)alloc((size_t)N * 64 * 2);
    unsigned short* Hb  = (unsigned short*)alloc((size_t)N * 64 * 2);
    unsigned short* Zb  = (unsigned short*)alloc((size_t)N * 40 * 2);
    unsigned short* Wb1 = (unsigned short*)alloc(8192 * 2);
    unsigned short* Wb2 = (unsigned short*)alloc(8192 * 2);
    unsigned short* Wb3 = (unsigned short*)alloc(6144 * 2);

    // build sorted CSR via dst-buckets, deterministic (no global atomics)
    prep_kernel<<<BBLK + 88 + 1024, 256, 0, stream>>>(dstA, cnts, E, NB, x, Xb, N * 64 / 8,
                                                      Wl1, Wr1, Wl2, Wr2, Wl3, Wr3, Wb1, Wb2, Wb3);
    colscan_kernel<<<NB, BBLK, 0, stream>>>(cnts, lpre, bcount);
    bscan_kernel<<<1, 1024, 0, stream>>>(bcount, bbase, NB, E);
    bin_kernel<<<BBLK, 512, 0, stream>>>(srcA, dstA, lpre, bbase, binned, E, NB);
    bsort_kernel<<<NB, 256, 0, stream>>>(binned, bbase, col, row_start, N);

    int gridA = (N + 31) / 32;
    int gridM = (N + 63) / 64;

    // layer 1
    agg64_kernel<<<gridA, 256, 0, stream>>>(Xb, row_start, col, AGG, N);
    linmfma12_kernel<<<gridM, 256, 0, stream>>>(AGG, Xb, Wb1, b1, Hb, N);

    // layer 2 (lin in-place on Hb: each block stages its own rows before writing)
    agg64_kernel<<<gridA, 256, 0, stream>>>(Hb, row_start, col, AGG, N);
    linmfma12_kernel<<<gridM, 256, 0, stream>>>(AGG, Hb, Wb2, b2, Hb, N);

    // layer 3: pre-transform (agg is linear), then agg(40) + self + log_softmax
    linmfma3_kernel<<<gridM, 256, 0, stream>>>(Hb, Wb3, b3, Zb, out, N);
    agg40lsm_kernel<<<gridA, 256, 0, stream>>>(Zb, row_start, col, out, N);
}

// Round 14
// 261.626 us; speedup vs baseline: 1.1585x; 1.0096x over previous
//
#include <hip/hip_runtime.h>
#include <hip/hip_bf16.h>
#include <math.h>

// GraphSAGE 3-layer, mean aggr, bf16 + MFMA. Round 13 (resubmit after broker
// timeout): src-locality CSR.
// r12 (264us) profile: all own kernels < 42us (harness fills dominate top-5);
// gathers (~95us total) hit L3 not L2 (12.8MB random working set > 4MB/XCD L2).
// Change: bsort counting-sort key = (dstLocal<<3)|(src>>14) -> within-node
// edges ordered by 2.1MB src-range => agg gathers become L2-resident.
// Everything else identical to r12.

#define BK_SHIFT 7
#define BK_NODES 128
#define NB_MAX   1024
#define BBLK     256      // bin blocks (rows of cnts)

typedef __attribute__((ext_vector_type(8))) short short8;
typedef __attribute__((ext_vector_type(4))) float f32x4;

__device__ inline float blo(unsigned v) { union { unsigned u; float f; } c; c.u = v << 16; return c.f; }
__device__ inline float bhi(unsigned v) { union { unsigned u; float f; } c; c.u = v & 0xFFFF0000u; return c.f; }
__device__ inline unsigned short f2bf(float f) {
    union { float f; unsigned u; } c; c.f = f;
    unsigned r = (c.u + 0x7FFFu + ((c.u >> 16) & 1u)) >> 16;
    return (unsigned short)r;
}

// ---------------- prep: per-block bucket counts (0..255) + wconv + xconv ----------------
__global__ __launch_bounds__(256) void prep_kernel(const int* __restrict__ dstA, int* __restrict__ cnts,
                                                   int E, int NB,
                                                   const float* __restrict__ x, unsigned short* __restrict__ Xb, int n8,
                                                   const float* __restrict__ Wl1, const float* __restrict__ Wr1,
                                                   const float* __restrict__ Wl2, const float* __restrict__ Wr2,
                                                   const float* __restrict__ Wl3, const float* __restrict__ Wr3,
                                                   unsigned short* __restrict__ Wb1,
                                                   unsigned short* __restrict__ Wb2,
                                                   unsigned short* __restrict__ Wb3) {
    int b = blockIdx.x, t = threadIdx.x;
    if (b < BBLK) {
        __shared__ int lc[NB_MAX];
        for (int i = t; i < NB_MAX; i += 256) lc[i] = 0;
        __syncthreads();
        int chunk = (E + BBLK - 1) / BBLK;
        int e0 = b * chunk, e1 = min(E, e0 + chunk);
        for (int e = e0 + t; e < e1; e += 256)
            atomicAdd(&lc[dstA[e] >> BK_SHIFT], 1);
        __syncthreads();
        for (int i = t; i < NB_MAX; i += 256) cnts[b * NB_MAX + i] = lc[i];
    } else if (b < BBLK + 88) {
        int i = (b - BBLK) * 256 + t;
        if (i < 8192) {
            int c = i >> 7, k = i & 127;
            float v = (k < 64) ? Wl1[c * 64 + k] : Wr1[c * 64 + k - 64];
            Wb1[i] = f2bf(v);
        } else if (i < 16384) {
            int j = i - 8192;
            int c = j >> 7, k = j & 127;
            float v = (k < 64) ? Wl2[c * 64 + k] : Wr2[c * 64 + k - 64];
            Wb2[j] = f2bf(v);
        } else if (i < 22528) {
            int j = i - 16384;
            int c = j >> 6, k = j & 63;
            float v = 0.f;
            if (c < 40) v = Wl3[c * 64 + k];
            else if (c >= 48 && c < 88) v = Wr3[(c - 48) * 64 + k];
            Wb3[j] = f2bf(v);
        }
    } else {
        for (int i = (b - (BBLK + 88)) * 256 + t; i < n8; i += 1024 * 256) {
            const float* p = x + (size_t)i * 8;
            float4 a = *(const float4*)p;
            float4 bq = *(const float4*)(p + 4);
            uint4 o;
            o.x = f2bf(a.x) | ((unsigned)f2bf(a.y) << 16);
            o.y = f2bf(a.z) | ((unsigned)f2bf(a.w) << 16);
            o.z = f2bf(bq.x) | ((unsigned)f2bf(bq.y) << 16);
            o.w = f2bf(bq.z) | ((unsigned)f2bf(bq.w) << 16);
            *(uint4*)(Xb + (size_t)i * 8) = o;
        }
    }
}

// ---------------- colscan: per-bucket exclusive prefix over the 256 bin-blocks ----------------
__global__ __launch_bounds__(256) void colscan_kernel(const int* __restrict__ cnts,
                                                      int* __restrict__ lpre,
                                                      int* __restrict__ bcount) {
    __shared__ int s[BBLK];
    int j = blockIdx.x, t = threadIdx.x;
    int v = cnts[t * NB_MAX + j];
    s[t] = v;
    __syncthreads();
    for (int off = 1; off < BBLK; off <<= 1) {
        int x = 0;
        if (t >= off) x = s[t - off];
        __syncthreads();
        s[t] += x;
        __syncthreads();
    }
    lpre[t * NB_MAX + j] = s[t] - v;
    if (t == BBLK - 1) bcount[j] = s[t];
}

// ---------------- scan bucket totals -> bbase ----------------
__global__ __launch_bounds__(1024) void bscan_kernel(const int* __restrict__ bcount,
                                                     int* __restrict__ bbase, int NB, int E) {
    __shared__ int s[1024];
    int t = threadIdx.x;
    int v = (t < NB) ? bcount[t] : 0;
    s[t] = v;
    __syncthreads();
    for (int off = 1; off < 1024; off <<= 1) {
        int x = 0;
        if (t >= off) x = s[t - off];
        __syncthreads();
        s[t] += x;
        __syncthreads();
    }
    if (t < NB) bbase[t] = s[t] - v;
    if (t == 0) bbase[NB] = E;
}

// ---------------- bin edges single-pass (src | dstLocal<<24), LDS cursors only ----------------
__global__ __launch_bounds__(512) void bin_kernel(const int* __restrict__ srcA,
                                                  const int* __restrict__ dstA,
                                                  const int* __restrict__ lpre,
                                                  const int* __restrict__ bbase,
                                                  int* __restrict__ binned, int E, int NB) {
    __shared__ int lc[NB_MAX];
    int b = blockIdx.x, t = threadIdx.x;
    for (int i = t; i < NB; i += 512)
        lc[i] = lpre[b * NB_MAX + i] + bbase[i];
    __syncthreads();
    int chunk = (E + BBLK - 1) / BBLK;
    int e0 = b * chunk, e1 = min(E, e0 + chunk);
    for (int e = e0 + t; e < e1; e += 512) {
        int d = dstA[e];
        int bk = d >> BK_SHIFT;
        int pos = atomicAdd(&lc[bk], 1);
        binned[pos] = srcA[e] | ((d & (BK_NODES - 1)) << 24);
    }
}

// ---------------- per-bucket counting sort -> sorted CSR ----------------
// Key = (dstLocal<<3) | (src>>14): groups each node's edges by 16K-node
// (2.1MB bf16) src-range for L2-resident gathers. 1024 keys, 256 threads.
__global__ __launch_bounds__(256) void bsort_kernel(const int* __restrict__ binned,
                                                    const int* __restrict__ bbase,
                                                    int* __restrict__ col,
                                                    int* __restrict__ row_start, int N) {
    __shared__ int cnt[1024];
    __shared__ int keybase[1024];
    __shared__ int ts[256];
    int b = blockIdx.x, t = threadIdx.x;
    int e0 = bbase[b], e1 = bbase[b + 1];
    for (int i = t; i < 1024; i += 256) cnt[i] = 0;
    __syncthreads();
    for (int e = e0 + t; e < e1; e += 256) {
        unsigned p = (unsigned)binned[e];
        int key = (int)((p >> 24) << 3) | (int)(((p & 0xFFFFFFu) >> 14) & 7u);
        atomicAdd(&cnt[key], 1);
    }
    __syncthreads();
    // scan 1024 keys: thread t owns keys 4t..4t+3
    int c0 = cnt[4 * t], c1 = cnt[4 * t + 1], c2 = cnt[4 * t + 2], c3 = cnt[4 * t + 3];
    int sum = c0 + c1 + c2 + c3;
    ts[t] = sum;
    __syncthreads();
    for (int off = 1; off < 256; off <<= 1) {
        int x = 0;
        if (t >= off) x = ts[t - off];
        __syncthreads();
        ts[t] += x;
        __syncthreads();
    }
    int run = e0 + ts[t] - sum;   // exclusive prefix of this thread's key group
    keybase[4 * t] = run;     run += c0;
    keybase[4 * t + 1] = run; run += c1;
    keybase[4 * t + 2] = run; run += c2;
    keybase[4 * t + 3] = run;
    __syncthreads();
    if (t < BK_NODES) {
        int node = b * BK_NODES + t;
        if (node < N) row_start[node] = keybase[t * 8];
    }
    if (b == gridDim.x - 1 && t == 0) row_start[N] = e1;
    for (int i = t; i < 1024; i += 256) cnt[i] = 0;
    __syncthreads();
    for (int e = e0 + t; e < e1; e += 256) {
        unsigned p = (unsigned)binned[e];
        int key = (int)((p >> 24) << 3) | (int)(((p & 0xFFFFFFu) >> 14) & 7u);
        int pos = keybase[key] + atomicAdd(&cnt[key], 1);
        col[pos] = p & 0xFFFFFF;
    }
}

// ---------------- mean aggregation, 64 bf16 dims: 8-lane group/node, uint4 ----------------
__global__ __launch_bounds__(256) void agg64_kernel(const unsigned short* __restrict__ X,
                                                    const int* __restrict__ rs,
                                                    const int* __restrict__ col,
                                                    unsigned short* __restrict__ OUT, int n) {
    int t = threadIdx.x;
    int node = blockIdx.x * 32 + (t >> 3);
    if (node >= n) return;
    int lane = t & 7;
    int s = rs[node], d = rs[node + 1] - s;
    const unsigned short* lp = X + lane * 8;
    float a0 = 0.f, a1 = 0.f, a2 = 0.f, a3 = 0.f, a4 = 0.f, a5 = 0.f, a6 = 0.f, a7 = 0.f;
    int j = 0;
    for (; j + 3 < d; j += 4) {
        int c0 = col[s + j], c1 = col[s + j + 1];
        int c2 = col[s + j + 2], c3 = col[s + j + 3];
        uint4 q0 = *(const uint4*)(lp + (size_t)c0 * 64);
        uint4 q1 = *(const uint4*)(lp + (size_t)c1 * 64);
        uint4 q2 = *(const uint4*)(lp + (size_t)c2 * 64);
        uint4 q3 = *(const uint4*)(lp + (size_t)c3 * 64);
        a0 += (blo(q0.x) + blo(q1.x)) + (blo(q2.x) + blo(q3.x));
        a1 += (bhi(q0.x) + bhi(q1.x)) + (bhi(q2.x) + bhi(q3.x));
        a2 += (blo(q0.y) + blo(q1.y)) + (blo(q2.y) + blo(q3.y));
        a3 += (bhi(q0.y) + bhi(q1.y)) + (bhi(q2.y) + bhi(q3.y));
        a4 += (blo(q0.z) + blo(q1.z)) + (blo(q2.z) + blo(q3.z));
        a5 += (bhi(q0.z) + bhi(q1.z)) + (bhi(q2.z) + bhi(q3.z));
        a6 += (blo(q0.w) + blo(q1.w)) + (blo(q2.w) + blo(q3.w));
        a7 += (bhi(q0.w) + bhi(q1.w)) + (bhi(q2.w) + bhi(q3.w));
    }
    for (; j < d; ++j) {
        int c0 = col[s + j];
        uint4 q0 = *(const uint4*)(lp + (size_t)c0 * 64);
        a0 += blo(q0.x); a1 += bhi(q0.x); a2 += blo(q0.y); a3 += bhi(q0.y);
        a4 += blo(q0.z); a5 += bhi(q0.z); a6 += blo(q0.w); a7 += bhi(q0.w);
    }
    float w = 1.f / (float)(d > 0 ? d : 1);
    a0 *= w; a1 *= w; a2 *= w; a3 *= w; a4 *= w; a5 *= w; a6 *= w; a7 *= w;
    uint4 o;
    o.x = f2bf(a0) | ((unsigned)f2bf(a1) << 16);
    o.y = f2bf(a2) | ((unsigned)f2bf(a3) << 16);
    o.z = f2bf(a4) | ((unsigned)f2bf(a5) << 16);
    o.w = f2bf(a6) | ((unsigned)f2bf(a7) << 16);
    *(uint4*)(OUT + (size_t)node * 64 + lane * 8) = o;
}

// ---------------- MFMA linear 1/2: OUT = relu([A|X]@Wb^T + b), K=128 ----------------
__global__ __launch_bounds__(256) void linmfma12_kernel(const unsigned short* __restrict__ A,
                                                        const unsigned short* __restrict__ X,
                                                        const unsigned short* __restrict__ Wb,
                                                        const float* __restrict__ bias,
                                                        unsigned short* __restrict__ OUT,
                                                        int N) {
    __shared__ unsigned short Ys[64][136];
    __shared__ unsigned short Ws[64][136];
    int t = threadIdx.x;
    int rowbase = blockIdx.x * 64;
#pragma unroll
    for (int it = 0; it < 4; ++it) {
        int idx = it * 256 + t;
        int row = idx >> 4, c = idx & 15;
        int grow = rowbase + row;
        if (grow >= N) grow = N - 1;
        const unsigned short* src = (c < 8) ? (A + (size_t)grow * 64 + c * 8)
                                            : (X + (size_t)grow * 64 + (c - 8) * 8);
        *(short8*)&Ys[row][c * 8] = *(const short8*)src;
        *(short8*)&Ws[row][c * 8] = *(const short8*)(Wb + (size_t)row * 128 + c * 8);
    }
    __syncthreads();
    int l = t & 63, w = t >> 6;
    int lrow = l & 15, lk = l >> 4;
    f32x4 acc0 = {0.f, 0.f, 0.f, 0.f};
    f32x4 acc1 = acc0, acc2 = acc0, acc3 = acc0;
#pragma unroll
    for (int kk = 0; kk < 4; ++kk) {
        int ko = kk * 32 + lk * 8;
        short8 a  = *(const short8*)&Ys[16 * w + lrow][ko];
        short8 b0 = *(const short8*)&Ws[lrow][ko];
        short8 b1 = *(const short8*)&Ws[16 + lrow][ko];
        short8 b2 = *(const short8*)&Ws[32 + lrow][ko];
        short8 b3 = *(const short8*)&Ws[48 + lrow][ko];
        acc0 = __builtin_amdgcn_mfma_f32_16x16x32_bf16(a, b0, acc0, 0, 0, 0);
        acc1 = __builtin_amdgcn_mfma_f32_16x16x32_bf16(a, b1, acc1, 0, 0, 0);
        acc2 = __builtin_amdgcn_mfma_f32_16x16x32_bf16(a, b2, acc2, 0, 0, 0);
        acc3 = __builtin_amdgcn_mfma_f32_16x16x32_bf16(a, b3, acc3, 0, 0, 0);
    }
#define EPI12(nt, accv)                                                   \
    {                                                                     \
        int colc = 16 * (nt) + lrow;                                      \
        float bv = bias[colc];                                            \
        _Pragma("unroll") for (int i = 0; i < 4; ++i) {                   \
            int grow = rowbase + 16 * w + lk * 4 + i;                     \
            if (grow < N) {                                               \
                float v = fmaxf(accv[i] + bv, 0.f);                       \
                OUT[(size_t)grow * 64 + colc] = f2bf(v);                  \
            }                                                             \
        }                                                                 \
    }
    EPI12(0, acc0) EPI12(1, acc1) EPI12(2, acc2) EPI12(3, acc3)
#undef EPI12
}

// ---------------- MFMA linear 3: Z = h2@Wl3^T (bf16), R = h2@Wr3^T + b3 (fp32) ----------------
__global__ __launch_bounds__(256) void linmfma3_kernel(const unsigned short* __restrict__ H,
                                                       const unsigned short* __restrict__ Wb3,
                                                       const float* __restrict__ b3,
                                                       unsigned short* __restrict__ Z,
                                                       float* __restrict__ R,
                                                       int N) {
    __shared__ unsigned short Ys[64][72];
    __shared__ unsigned short Ws[96][72];
    int t = threadIdx.x;
    int rowbase = blockIdx.x * 64;
#pragma unroll
    for (int it = 0; it < 2; ++it) {
        int idx = it * 256 + t;
        int row = idx >> 3, c = idx & 7;
        int grow = rowbase + row;
        if (grow >= N) grow = N - 1;
        *(short8*)&Ys[row][c * 8] = *(const short8*)(H + (size_t)grow * 64 + c * 8);
    }
#pragma unroll
    for (int it = 0; it < 3; ++it) {
        int idx = it * 256 + t;
        int row = idx >> 3, c = idx & 7;
        *(short8*)&Ws[row][c * 8] = *(const short8*)(Wb3 + (size_t)row * 64 + c * 8);
    }
    __syncthreads();
    int l = t & 63, w = t >> 6;
    int lrow = l & 15, lk = l >> 4;
    f32x4 acc0 = {0.f, 0.f, 0.f, 0.f};
    f32x4 acc1 = acc0, acc2 = acc0, acc3 = acc0, acc4 = acc0, acc5 = acc0;
#pragma unroll
    for (int kk = 0; kk < 2; ++kk) {
        int ko = kk * 32 + lk * 8;
        short8 a  = *(const short8*)&Ys[16 * w + lrow][ko];
        short8 b0 = *(const short8*)&Ws[lrow][ko];
        short8 b1 = *(const short8*)&Ws[16 + lrow][ko];
        short8 b2 = *(const short8*)&Ws[32 + lrow][ko];
        short8 b3f = *(const short8*)&Ws[48 + lrow][ko];
        short8 b4 = *(const short8*)&Ws[64 + lrow][ko];
        short8 b5 = *(const short8*)&Ws[80 + lrow][ko];
        acc0 = __builtin_amdgcn_mfma_f32_16x16x32_bf16(a, b0, acc0, 0, 0, 0);
        acc1 = __builtin_amdgcn_mfma_f32_16x16x32_bf16(a, b1, acc1, 0, 0, 0);
        acc2 = __builtin_amdgcn_mfma_f32_16x16x32_bf16(a, b2, acc2, 0, 0, 0);
        acc3 = __builtin_amdgcn_mfma_f32_16x16x32_bf16(a, b3f, acc3, 0, 0, 0);
        acc4 = __builtin_amdgcn_mfma_f32_16x16x32_bf16(a, b4, acc4, 0, 0, 0);
        acc5 = __builtin_amdgcn_mfma_f32_16x16x32_bf16(a, b5, acc5, 0, 0, 0);
    }
#define EPI3(nt, accv)                                                     \
    {                                                                      \
        int colc = 16 * (nt) + lrow;                                       \
        _Pragma("unroll") for (int i = 0; i < 4; ++i) {                    \
            int grow = rowbase + 16 * w + lk * 4 + i;                      \
            if (grow < N) {                                                \
                float v = accv[i];                                         \
                if (colc < 40) {                                           \
                    Z[(size_t)grow * 40 + colc] = f2bf(v);                 \
                } else if (colc >= 48 && colc < 88) {                      \
                    R[(size_t)grow * 40 + (colc - 48)] = v + b3[colc - 48];\
                }                                                          \
            }                                                              \
        }                                                                  \
    }
    EPI3(0, acc0) EPI3(1, acc1) EPI3(2, acc2) EPI3(3, acc3) EPI3(4, acc4) EPI3(5, acc5)
#undef EPI3
}

// ---------------- agg(40 bf16) + self add + fused log_softmax: 8-lane group/node ----------------
__global__ __launch_bounds__(256) void agg40lsm_kernel(const unsigned short* __restrict__ Z,
                                                       const int* __restrict__ rs,
                                                       const int* __restrict__ col,
                                                       float* __restrict__ out, int n) {
    int t = threadIdx.x;
    int node = blockIdx.x * 32 + (t >> 3);
    if (node >= n) return;
    int lane = t & 7;
    bool act = lane < 5;
    int s = rs[node], d = rs[node + 1] - s;
    const unsigned short* lp = Z + lane * 8;
    float a0 = 0.f, a1 = 0.f, a2 = 0.f, a3 = 0.f, a4 = 0.f, a5 = 0.f, a6 = 0.f, a7 = 0.f;
    int j = 0;
    for (; j + 3 < d; j += 4) {
        int c0 = col[s + j], c1 = col[s + j + 1];
        int c2 = col[s + j + 2], c3 = col[s + j + 3];
        if (act) {
            uint4 q0 = *(const uint4*)(lp + (size_t)c0 * 40);
            uint4 q1 = *(const uint4*)(lp + (size_t)c1 * 40);
            uint4 q2 = *(const uint4*)(lp + (size_t)c2 * 40);
            uint4 q3 = *(const uint4*)(lp + (size_t)c3 * 40);
            a0 += (blo(q0.x) + blo(q1.x)) + (blo(q2.x) + blo(q3.x));
            a1 += (bhi(q0.x) + bhi(q1.x)) + (bhi(q2.x) + bhi(q3.x));
            a2 += (blo(q0.y) + blo(q1.y)) + (blo(q2.y) + blo(q3.y));
            a3 += (bhi(q0.y) + bhi(q1.y)) + (bhi(q2.y) + bhi(q3.y));
            a4 += (blo(q0.z) + blo(q1.z)) + (blo(q2.z) + blo(q3.z));
            a5 += (bhi(q0.z) + bhi(q1.z)) + (bhi(q2.z) + bhi(q3.z));
            a6 += (blo(q0.w) + blo(q1.w)) + (blo(q2.w) + blo(q3.w));
            a7 += (bhi(q0.w) + bhi(q1.w)) + (bhi(q2.w) + bhi(q3.w));
        }
    }
    for (; j < d; ++j) {
        int c0 = col[s + j];
        if (act) {
            uint4 q0 = *(const uint4*)(lp + (size_t)c0 * 40);
            a0 += blo(q0.x); a1 += bhi(q0.x); a2 += blo(q0.y); a3 += bhi(q0.y);
            a4 += blo(q0.z); a5 += bhi(q0.z); a6 += blo(q0.w); a7 += bhi(q0.w);
        }
    }
    float w = 1.f / (float)(d > 0 ? d : 1);
    if (act) {
        float* op = out + (size_t)node * 40 + lane * 8;
        float4 r0 = *(const float4*)op;
        float4 r1 = *(const float4*)(op + 4);
        a0 = a0 * w + r0.x; a1 = a1 * w + r0.y; a2 = a2 * w + r0.z; a3 = a3 * w + r0.w;
        a4 = a4 * w + r1.x; a5 = a5 * w + r1.y; a6 = a6 * w + r1.z; a7 = a7 * w + r1.w;
    }
    float mx = act ? fmaxf(fmaxf(fmaxf(a0, a1), fmaxf(a2, a3)),
                           fmaxf(fmaxf(a4, a5), fmaxf(a6, a7))) : -3.4e38f;
#pragma unroll
    for (int off = 1; off < 8; off <<= 1) mx = fmaxf(mx, __shfl_xor(mx, off, 8));
    float ssum = act ? (expf(a0 - mx) + expf(a1 - mx) + expf(a2 - mx) + expf(a3 - mx) +
                        expf(a4 - mx) + expf(a5 - mx) + expf(a6 - mx) + expf(a7 - mx)) : 0.f;
#pragma unroll
    for (int off = 1; off < 8; off <<= 1) ssum += __shfl_xor(ssum, off, 8);
    float lg = mx + logf(ssum);
    if (act) {
        float* op = out + (size_t)node * 40 + lane * 8;
        float4 o0, o1;
        o0.x = a0 - lg; o0.y = a1 - lg; o0.z = a2 - lg; o0.w = a3 - lg;
        o1.x = a4 - lg; o1.y = a5 - lg; o1.z = a6 - lg; o1.w = a7 - lg;
        *(float4*)op = o0;
        *(float4*)(op + 4) = o1;
    }
}

// ---------------- launch ----------------
extern "C" void kernel_launch(void* const* d_in, const int* in_sizes, int n_in,
                              void* d_out, int out_size, void* d_ws, size_t ws_size,
                              hipStream_t stream) {
    const float* x   = (const float*)d_in[0];
    const int*   ei  = (const int*)d_in[1];
    const float* Wl1 = (const float*)d_in[2];
    const float* Wr1 = (const float*)d_in[3];
    const float* b1  = (const float*)d_in[4];
    const float* Wl2 = (const float*)d_in[5];
    const float* Wr2 = (const float*)d_in[6];
    const float* b2  = (const float*)d_in[7];
    const float* Wl3 = (const float*)d_in[8];
    const float* Wr3 = (const float*)d_in[9];
    const float* b3  = (const float*)d_in[10];
    float* out = (float*)d_out;

    const int N = in_sizes[0] / 64;
    const int E = in_sizes[1] / 2;
    const int NB = (N + BK_NODES - 1) / BK_NODES;
    const int* srcA = ei;
    const int* dstA = ei + E;

    char* ws = (char*)d_ws;
    size_t off = 0;
    auto alloc = [&](size_t bytes) {
        off = (off + 255) & ~(size_t)255;
        char* p = ws + off;
        off += bytes;
        return p;
    };
    int* cnts      = (int*)alloc((size_t)BBLK * NB_MAX * 4);
    int* lpre      = (int*)alloc((size_t)BBLK * NB_MAX * 4);
    int* bcount    = (int*)alloc((size_t)(NB_MAX + 1) * 4);
    int* bbase     = (int*)alloc((size_t)(NB_MAX + 1) * 4);
    int* binned    = (int*)alloc((size_t)E * 4);
    int* col       = (int*)alloc((size_t)E * 4);
    int* row_start = (int*)alloc((size_t)(N + 1) * 4);
    unsigned short* Xb  = (unsigned short*)alloc((size_t)N * 64 * 2);
    unsigned short* AGG = (unsigned short*)alloc((size_t)N * 64 * 2);
    unsigned short* Hb  = (unsigned short*)alloc((size_t)N * 64 * 2);
    unsigned short* Zb  = (unsigned short*)alloc((size_t)N * 40 * 2);
    unsigned short* Wb1 = (unsigned short*)alloc(8192 * 2);
    unsigned short* Wb2 = (unsigned short*)alloc(8192 * 2);
    unsigned short* Wb3 = (unsigned short*)alloc(6144 * 2);

    // build sorted CSR via dst-buckets, deterministic (no global atomics)
    prep_kernel<<<BBLK + 88 + 1024, 256, 0, stream>>>(dstA, cnts, E, NB, x, Xb, N * 64 / 8,
                                                      Wl1, Wr1, Wl2, Wr2, Wl3, Wr3, Wb1, Wb2, Wb3);
    colscan_kernel<<<NB, BBLK, 0, stream>>>(cnts, lpre, bcount);
    bscan_kernel<<<1, 1024, 0, stream>>>(bcount, bbase, NB, E);
    bin_kernel<<<BBLK, 512, 0, stream>>>(srcA, dstA, lpre, bbase, binned, E, NB);
    bsort_kernel<<<NB, 256, 0, stream>>>(binned, bbase, col, row_start, N);

    int gridA = (N + 31) / 32;
    int gridM = (N + 63) / 64;

    // layer 1
    agg64_kernel<<<gridA, 256, 0, stream>>>(Xb, row_start, col, AGG, N);
    linmfma12_kernel<<<gridM, 256, 0, stream>>>(AGG, Xb, Wb1, b1, Hb, N);

    // layer 2 (lin in-place on Hb: each block stages its own rows before writing)
    agg64_kernel<<<gridA, 256, 0, stream>>>(Hb, row_start, col, AGG, N);
    linmfma12_kernel<<<gridM, 256, 0, stream>>>(AGG, Hb, Wb2, b2, Hb, N);

    // layer 3: pre-transform (agg is linear), then agg(40) + self + log_softmax
    linmfma3_kernel<<<gridM, 256, 0, stream>>>(Hb, Wb3, b3, Zb, out, N);
    agg40lsm_kernel<<<gridA, 256, 0, stream>>>(Zb, row_start, col, out, N);
}

// Round 15
// 259.754 us; speedup vs baseline: 1.1669x; 1.0072x over previous
//
#include <hip/hip_runtime.h>
#include <hip/hip_bf16.h>
#include <math.h>

// GraphSAGE 3-layer, mean aggr, bf16 + MFMA. Round 15: fuse L2-linear with
// L3 pre-transform (lin23). h2 round-trips through LDS (wave-local rows:
// MFMA epilogue rows == stage-2 A-fragment rows -> no extra barrier), saving
// the 25.6MB Hb h2 write+read and one launch. Build pipeline = r12/r14
// (deterministic binning + src-locality bsort, 262us proven).

#define BK_SHIFT 7
#define BK_NODES 128
#define NB_MAX   1024
#define BBLK     256      // bin blocks (rows of cnts)

typedef __attribute__((ext_vector_type(8))) short short8;
typedef __attribute__((ext_vector_type(4))) float f32x4;

__device__ inline float blo(unsigned v) { union { unsigned u; float f; } c; c.u = v << 16; return c.f; }
__device__ inline float bhi(unsigned v) { union { unsigned u; float f; } c; c.u = v & 0xFFFF0000u; return c.f; }
__device__ inline unsigned short f2bf(float f) {
    union { float f; unsigned u; } c; c.f = f;
    unsigned r = (c.u + 0x7FFFu + ((c.u >> 16) & 1u)) >> 16;
    return (unsigned short)r;
}

// ---------------- prep: per-block bucket counts (0..255) + wconv + xconv ----------------
__global__ __launch_bounds__(256) void prep_kernel(const int* __restrict__ dstA, int* __restrict__ cnts,
                                                   int E, int NB,
                                                   const float* __restrict__ x, unsigned short* __restrict__ Xb, int n8,
                                                   const float* __restrict__ Wl1, const float* __restrict__ Wr1,
                                                   const float* __restrict__ Wl2, const float* __restrict__ Wr2,
                                                   const float* __restrict__ Wl3, const float* __restrict__ Wr3,
                                                   unsigned short* __restrict__ Wb1,
                                                   unsigned short* __restrict__ Wb2,
                                                   unsigned short* __restrict__ Wb3) {
    int b = blockIdx.x, t = threadIdx.x;
    if (b < BBLK) {
        __shared__ int lc[NB_MAX];
        for (int i = t; i < NB_MAX; i += 256) lc[i] = 0;
        __syncthreads();
        int chunk = (E + BBLK - 1) / BBLK;
        int e0 = b * chunk, e1 = min(E, e0 + chunk);
        for (int e = e0 + t; e < e1; e += 256)
            atomicAdd(&lc[dstA[e] >> BK_SHIFT], 1);
        __syncthreads();
        for (int i = t; i < NB_MAX; i += 256) cnts[b * NB_MAX + i] = lc[i];
    } else if (b < BBLK + 88) {
        int i = (b - BBLK) * 256 + t;
        if (i < 8192) {
            int c = i >> 7, k = i & 127;
            float v = (k < 64) ? Wl1[c * 64 + k] : Wr1[c * 64 + k - 64];
            Wb1[i] = f2bf(v);
        } else if (i < 16384) {
            int j = i - 8192;
            int c = j >> 7, k = j & 127;
            float v = (k < 64) ? Wl2[c * 64 + k] : Wr2[c * 64 + k - 64];
            Wb2[j] = f2bf(v);
        } else if (i < 22528) {
            int j = i - 16384;
            int c = j >> 6, k = j & 63;
            float v = 0.f;
            if (c < 40) v = Wl3[c * 64 + k];
            else if (c >= 48 && c < 88) v = Wr3[(c - 48) * 64 + k];
            Wb3[j] = f2bf(v);
        }
    } else {
        for (int i = (b - (BBLK + 88)) * 256 + t; i < n8; i += 1024 * 256) {
            const float* p = x + (size_t)i * 8;
            float4 a = *(const float4*)p;
            float4 bq = *(const float4*)(p + 4);
            uint4 o;
            o.x = f2bf(a.x) | ((unsigned)f2bf(a.y) << 16);
            o.y = f2bf(a.z) | ((unsigned)f2bf(a.w) << 16);
            o.z = f2bf(bq.x) | ((unsigned)f2bf(bq.y) << 16);
            o.w = f2bf(bq.z) | ((unsigned)f2bf(bq.w) << 16);
            *(uint4*)(Xb + (size_t)i * 8) = o;
        }
    }
}

// ---------------- colscan: per-bucket exclusive prefix over the 256 bin-blocks ----------------
__global__ __launch_bounds__(256) void colscan_kernel(const int* __restrict__ cnts,
                                                      int* __restrict__ lpre,
                                                      int* __restrict__ bcount) {
    __shared__ int s[BBLK];
    int j = blockIdx.x, t = threadIdx.x;
    int v = cnts[t * NB_MAX + j];
    s[t] = v;
    __syncthreads();
    for (int off = 1; off < BBLK; off <<= 1) {
        int x = 0;
        if (t >= off) x = s[t - off];
        __syncthreads();
        s[t] += x;
        __syncthreads();
    }
    lpre[t * NB_MAX + j] = s[t] - v;
    if (t == BBLK - 1) bcount[j] = s[t];
}

// ---------------- scan bucket totals -> bbase ----------------
__global__ __launch_bounds__(1024) void bscan_kernel(const int* __restrict__ bcount,
                                                     int* __restrict__ bbase, int NB, int E) {
    __shared__ int s[1024];
    int t = threadIdx.x;
    int v = (t < NB) ? bcount[t] : 0;
    s[t] = v;
    __syncthreads();
    for (int off = 1; off < 1024; off <<= 1) {
        int x = 0;
        if (t >= off) x = s[t - off];
        __syncthreads();
        s[t] += x;
        __syncthreads();
    }
    if (t < NB) bbase[t] = s[t] - v;
    if (t == 0) bbase[NB] = E;
}

// ---------------- bin edges single-pass (src | dstLocal<<24), LDS cursors only ----------------
__global__ __launch_bounds__(512) void bin_kernel(const int* __restrict__ srcA,
                                                  const int* __restrict__ dstA,
                                                  const int* __restrict__ lpre,
                                                  const int* __restrict__ bbase,
                                                  int* __restrict__ binned, int E, int NB) {
    __shared__ int lc[NB_MAX];
    int b = blockIdx.x, t = threadIdx.x;
    for (int i = t; i < NB; i += 512)
        lc[i] = lpre[b * NB_MAX + i] + bbase[i];
    __syncthreads();
    int chunk = (E + BBLK - 1) / BBLK;
    int e0 = b * chunk, e1 = min(E, e0 + chunk);
    for (int e = e0 + t; e < e1; e += 512) {
        int d = dstA[e];
        int bk = d >> BK_SHIFT;
        int pos = atomicAdd(&lc[bk], 1);
        binned[pos] = srcA[e] | ((d & (BK_NODES - 1)) << 24);
    }
}

// ---------------- per-bucket counting sort -> sorted CSR ----------------
// Key = (dstLocal<<3) | (src>>14): groups each node's edges by 16K-node
// src-range (deterministic order). 1024 keys, 256 threads.
__global__ __launch_bounds__(256) void bsort_kernel(const int* __restrict__ binned,
                                                    const int* __restrict__ bbase,
                                                    int* __restrict__ col,
                                                    int* __restrict__ row_start, int N) {
    __shared__ int cnt[1024];
    __shared__ int keybase[1024];
    __shared__ int ts[256];
    int b = blockIdx.x, t = threadIdx.x;
    int e0 = bbase[b], e1 = bbase[b + 1];
    for (int i = t; i < 1024; i += 256) cnt[i] = 0;
    __syncthreads();
    for (int e = e0 + t; e < e1; e += 256) {
        unsigned p = (unsigned)binned[e];
        int key = (int)((p >> 24) << 3) | (int)(((p & 0xFFFFFFu) >> 14) & 7u);
        atomicAdd(&cnt[key], 1);
    }
    __syncthreads();
    int c0 = cnt[4 * t], c1 = cnt[4 * t + 1], c2 = cnt[4 * t + 2], c3 = cnt[4 * t + 3];
    int sum = c0 + c1 + c2 + c3;
    ts[t] = sum;
    __syncthreads();
    for (int off = 1; off < 256; off <<= 1) {
        int x = 0;
        if (t >= off) x = ts[t - off];
        __syncthreads();
        ts[t] += x;
        __syncthreads();
    }
    int run = e0 + ts[t] - sum;
    keybase[4 * t] = run;     run += c0;
    keybase[4 * t + 1] = run; run += c1;
    keybase[4 * t + 2] = run; run += c2;
    keybase[4 * t + 3] = run;
    __syncthreads();
    if (t < BK_NODES) {
        int node = b * BK_NODES + t;
        if (node < N) row_start[node] = keybase[t * 8];
    }
    if (b == gridDim.x - 1 && t == 0) row_start[N] = e1;
    for (int i = t; i < 1024; i += 256) cnt[i] = 0;
    __syncthreads();
    for (int e = e0 + t; e < e1; e += 256) {
        unsigned p = (unsigned)binned[e];
        int key = (int)((p >> 24) << 3) | (int)(((p & 0xFFFFFFu) >> 14) & 7u);
        int pos = keybase[key] + atomicAdd(&cnt[key], 1);
        col[pos] = p & 0xFFFFFF;
    }
}

// ---------------- mean aggregation, 64 bf16 dims: 8-lane group/node, uint4 ----------------
__global__ __launch_bounds__(256) void agg64_kernel(const unsigned short* __restrict__ X,
                                                    const int* __restrict__ rs,
                                                    const int* __restrict__ col,
                                                    unsigned short* __restrict__ OUT, int n) {
    int t = threadIdx.x;
    int node = blockIdx.x * 32 + (t >> 3);
    if (node >= n) return;
    int lane = t & 7;
    int s = rs[node], d = rs[node + 1] - s;
    const unsigned short* lp = X + lane * 8;
    float a0 = 0.f, a1 = 0.f, a2 = 0.f, a3 = 0.f, a4 = 0.f, a5 = 0.f, a6 = 0.f, a7 = 0.f;
    int j = 0;
    for (; j + 3 < d; j += 4) {
        int c0 = col[s + j], c1 = col[s + j + 1];
        int c2 = col[s + j + 2], c3 = col[s + j + 3];
        uint4 q0 = *(const uint4*)(lp + (size_t)c0 * 64);
        uint4 q1 = *(const uint4*)(lp + (size_t)c1 * 64);
        uint4 q2 = *(const uint4*)(lp + (size_t)c2 * 64);
        uint4 q3 = *(const uint4*)(lp + (size_t)c3 * 64);
        a0 += (blo(q0.x) + blo(q1.x)) + (blo(q2.x) + blo(q3.x));
        a1 += (bhi(q0.x) + bhi(q1.x)) + (bhi(q2.x) + bhi(q3.x));
        a2 += (blo(q0.y) + blo(q1.y)) + (blo(q2.y) + blo(q3.y));
        a3 += (bhi(q0.y) + bhi(q1.y)) + (bhi(q2.y) + bhi(q3.y));
        a4 += (blo(q0.z) + blo(q1.z)) + (blo(q2.z) + blo(q3.z));
        a5 += (bhi(q0.z) + bhi(q1.z)) + (bhi(q2.z) + bhi(q3.z));
        a6 += (blo(q0.w) + blo(q1.w)) + (blo(q2.w) + blo(q3.w));
        a7 += (bhi(q0.w) + bhi(q1.w)) + (bhi(q2.w) + bhi(q3.w));
    }
    for (; j < d; ++j) {
        int c0 = col[s + j];
        uint4 q0 = *(const uint4*)(lp + (size_t)c0 * 64);
        a0 += blo(q0.x); a1 += bhi(q0.x); a2 += blo(q0.y); a3 += bhi(q0.y);
        a4 += blo(q0.z); a5 += bhi(q0.z); a6 += blo(q0.w); a7 += bhi(q0.w);
    }
    float w = 1.f / (float)(d > 0 ? d : 1);
    a0 *= w; a1 *= w; a2 *= w; a3 *= w; a4 *= w; a5 *= w; a6 *= w; a7 *= w;
    uint4 o;
    o.x = f2bf(a0) | ((unsigned)f2bf(a1) << 16);
    o.y = f2bf(a2) | ((unsigned)f2bf(a3) << 16);
    o.z = f2bf(a4) | ((unsigned)f2bf(a5) << 16);
    o.w = f2bf(a6) | ((unsigned)f2bf(a7) << 16);
    *(uint4*)(OUT + (size_t)node * 64 + lane * 8) = o;
}

// ---------------- MFMA linear 1: OUT = relu([A|X]@Wb^T + b), K=128 ----------------
__global__ __launch_bounds__(256) void linmfma12_kernel(const unsigned short* __restrict__ A,
                                                        const unsigned short* __restrict__ X,
                                                        const unsigned short* __restrict__ Wb,
                                                        const float* __restrict__ bias,
                                                        unsigned short* __restrict__ OUT,
                                                        int N) {
    __shared__ unsigned short Ys[64][136];
    __shared__ unsigned short Ws[64][136];
    int t = threadIdx.x;
    int rowbase = blockIdx.x * 64;
#pragma unroll
    for (int it = 0; it < 4; ++it) {
        int idx = it * 256 + t;
        int row = idx >> 4, c = idx & 15;
        int grow = rowbase + row;
        if (grow >= N) grow = N - 1;
        const unsigned short* src = (c < 8) ? (A + (size_t)grow * 64 + c * 8)
                                            : (X + (size_t)grow * 64 + (c - 8) * 8);
        *(short8*)&Ys[row][c * 8] = *(const short8*)src;
        *(short8*)&Ws[row][c * 8] = *(const short8*)(Wb + (size_t)row * 128 + c * 8);
    }
    __syncthreads();
    int l = t & 63, w = t >> 6;
    int lrow = l & 15, lk = l >> 4;
    f32x4 acc0 = {0.f, 0.f, 0.f, 0.f};
    f32x4 acc1 = acc0, acc2 = acc0, acc3 = acc0;
#pragma unroll
    for (int kk = 0; kk < 4; ++kk) {
        int ko = kk * 32 + lk * 8;
        short8 a  = *(const short8*)&Ys[16 * w + lrow][ko];
        short8 b0 = *(const short8*)&Ws[lrow][ko];
        short8 b1 = *(const short8*)&Ws[16 + lrow][ko];
        short8 b2 = *(const short8*)&Ws[32 + lrow][ko];
        short8 b3 = *(const short8*)&Ws[48 + lrow][ko];
        acc0 = __builtin_amdgcn_mfma_f32_16x16x32_bf16(a, b0, acc0, 0, 0, 0);
        acc1 = __builtin_amdgcn_mfma_f32_16x16x32_bf16(a, b1, acc1, 0, 0, 0);
        acc2 = __builtin_amdgcn_mfma_f32_16x16x32_bf16(a, b2, acc2, 0, 0, 0);
        acc3 = __builtin_amdgcn_mfma_f32_16x16x32_bf16(a, b3, acc3, 0, 0, 0);
    }
#define EPI12(nt, accv)                                                   \
    {                                                                     \
        int colc = 16 * (nt) + lrow;                                      \
        float bv = bias[colc];                                            \
        _Pragma("unroll") for (int i = 0; i < 4; ++i) {                   \
            int grow = rowbase + 16 * w + lk * 4 + i;                     \
            if (grow < N) {                                               \
                float v = fmaxf(accv[i] + bv, 0.f);                       \
                OUT[(size_t)grow * 64 + colc] = f2bf(v);                  \
            }                                                             \
        }                                                                 \
    }
    EPI12(0, acc0) EPI12(1, acc1) EPI12(2, acc2) EPI12(3, acc3)
#undef EPI12
}

// ---------------- fused L2 linear + L3 pre-transform ----------------
// Stage 1: h2 = relu([AGG|h1]@Wb2^T + b2)  (K=128) -> written bf16 into
//          Ys cols 0..63 (wave-local rows: epilogue rows == stage-2 A rows,
//          so only per-wave lgkmcnt ordering is needed, no barrier).
// Stage 2: Z = h2@Wl3^T (bf16), R = h2@Wr3^T + b3 (fp32)  (K=64, Wb3[96][64]).
__global__ __launch_bounds__(256) void lin23_kernel(const unsigned short* __restrict__ A,
                                                    const unsigned short* __restrict__ X,
                                                    const unsigned short* __restrict__ Wb2,
                                                    const float* __restrict__ bias2,
                                                    const unsigned short* __restrict__ Wb3,
                                                    const float* __restrict__ b3,
                                                    unsigned short* __restrict__ Z,
                                                    float* __restrict__ R,
                                                    int N) {
    __shared__ unsigned short Ys[64][136];
    __shared__ unsigned short Ws[64][136];
    __shared__ unsigned short W3[96][72];
    int t = threadIdx.x;
    int rowbase = blockIdx.x * 64;
#pragma unroll
    for (int it = 0; it < 4; ++it) {
        int idx = it * 256 + t;
        int row = idx >> 4, c = idx & 15;
        int grow = rowbase + row;
        if (grow >= N) grow = N - 1;
        const unsigned short* src = (c < 8) ? (A + (size_t)grow * 64 + c * 8)
                                            : (X + (size_t)grow * 64 + (c - 8) * 8);
        *(short8*)&Ys[row][c * 8] = *(const short8*)src;
        *(short8*)&Ws[row][c * 8] = *(const short8*)(Wb2 + (size_t)row * 128 + c * 8);
    }
#pragma unroll
    for (int it = 0; it < 3; ++it) {
        int idx = it * 256 + t;        // 768 chunks = 96 rows x 8
        int row = idx >> 3, c = idx & 7;
        *(short8*)&W3[row][c * 8] = *(const short8*)(Wb3 + (size_t)row * 64 + c * 8);
    }
    __syncthreads();
    int l = t & 63, w = t >> 6;
    int lrow = l & 15, lk = l >> 4;
    // ---- stage 1: K=128 vs Wb2 ----
    f32x4 acc0 = {0.f, 0.f, 0.f, 0.f};
    f32x4 acc1 = acc0, acc2 = acc0, acc3 = acc0;
#pragma unroll
    for (int kk = 0; kk < 4; ++kk) {
        int ko = kk * 32 + lk * 8;
        short8 a  = *(const short8*)&Ys[16 * w + lrow][ko];
        short8 b0 = *(const short8*)&Ws[lrow][ko];
        short8 b1 = *(const short8*)&Ws[16 + lrow][ko];
        short8 b2 = *(const short8*)&Ws[32 + lrow][ko];
        short8 b3v = *(const short8*)&Ws[48 + lrow][ko];
        acc0 = __builtin_amdgcn_mfma_f32_16x16x32_bf16(a, b0, acc0, 0, 0, 0);
        acc1 = __builtin_amdgcn_mfma_f32_16x16x32_bf16(a, b1, acc1, 0, 0, 0);
        acc2 = __builtin_amdgcn_mfma_f32_16x16x32_bf16(a, b2, acc2, 0, 0, 0);
        acc3 = __builtin_amdgcn_mfma_f32_16x16x32_bf16(a, b3v, acc3, 0, 0, 0);
    }
    // h2 -> LDS (cols 0..63 of this wave's OWN 16 rows; unconditional)
#define EPIH(nt, accv)                                                    \
    {                                                                     \
        int colc = 16 * (nt) + lrow;                                      \
        float bv = bias2[colc];                                           \
        _Pragma("unroll") for (int i = 0; i < 4; ++i) {                   \
            int row = 16 * w + lk * 4 + i;                                \
            Ys[row][colc] = f2bf(fmaxf(accv[i] + bv, 0.f));               \
        }                                                                 \
    }
    EPIH(0, acc0) EPIH(1, acc1) EPIH(2, acc2) EPIH(3, acc3)
#undef EPIH
    // ---- stage 2: K=64 vs Wb3 (reads only this wave's own rows) ----
    f32x4 z0 = {0.f, 0.f, 0.f, 0.f};
    f32x4 z1 = z0, z2 = z0, z3 = z0, z4 = z0, z5 = z0;
#pragma unroll
    for (int kk = 0; kk < 2; ++kk) {
        int ko = kk * 32 + lk * 8;
        short8 a  = *(const short8*)&Ys[16 * w + lrow][ko];
        short8 b0 = *(const short8*)&W3[lrow][ko];
        short8 b1 = *(const short8*)&W3[16 + lrow][ko];
        short8 b2 = *(const short8*)&W3[32 + lrow][ko];
        short8 b3v = *(const short8*)&W3[48 + lrow][ko];
        short8 b4 = *(const short8*)&W3[64 + lrow][ko];
        short8 b5 = *(const short8*)&W3[80 + lrow][ko];
        z0 = __builtin_amdgcn_mfma_f32_16x16x32_bf16(a, b0, z0, 0, 0, 0);
        z1 = __builtin_amdgcn_mfma_f32_16x16x32_bf16(a, b1, z1, 0, 0, 0);
        z2 = __builtin_amdgcn_mfma_f32_16x16x32_bf16(a, b2, z2, 0, 0, 0);
        z3 = __builtin_amdgcn_mfma_f32_16x16x32_bf16(a, b3v, z3, 0, 0, 0);
        z4 = __builtin_amdgcn_mfma_f32_16x16x32_bf16(a, b4, z4, 0, 0, 0);
        z5 = __builtin_amdgcn_mfma_f32_16x16x32_bf16(a, b5, z5, 0, 0, 0);
    }
#define EPI3(nt, accv)                                                     \
    {                                                                      \
        int colc = 16 * (nt) + lrow;                                       \
        _Pragma("unroll") for (int i = 0; i < 4; ++i) {                    \
            int grow = rowbase + 16 * w + lk * 4 + i;                      \
            if (grow < N) {                                                \
                float v = accv[i];                                         \
                if (colc < 40) {                                           \
                    Z[(size_t)grow * 40 + colc] = f2bf(v);                 \
                } else if (colc >= 48 && colc < 88) {                      \
                    R[(size_t)grow * 40 + (colc - 48)] = v + b3[colc - 48];\
                }                                                          \
            }                                                              \
        }                                                                  \
    }
    EPI3(0, z0) EPI3(1, z1) EPI3(2, z2) EPI3(3, z3) EPI3(4, z4) EPI3(5, z5)
#undef EPI3
}

// ---------------- agg(40 bf16) + self add + fused log_softmax: 8-lane group/node ----------------
__global__ __launch_bounds__(256) void agg40lsm_kernel(const unsigned short* __restrict__ Z,
                                                       const int* __restrict__ rs,
                                                       const int* __restrict__ col,
                                                       float* __restrict__ out, int n) {
    int t = threadIdx.x;
    int node = blockIdx.x * 32 + (t >> 3);
    if (node >= n) return;
    int lane = t & 7;
    bool act = lane < 5;
    int s = rs[node], d = rs[node + 1] - s;
    const unsigned short* lp = Z + lane * 8;
    float a0 = 0.f, a1 = 0.f, a2 = 0.f, a3 = 0.f, a4 = 0.f, a5 = 0.f, a6 = 0.f, a7 = 0.f;
    int j = 0;
    for (; j + 3 < d; j += 4) {
        int c0 = col[s + j], c1 = col[s + j + 1];
        int c2 = col[s + j + 2], c3 = col[s + j + 3];
        if (act) {
            uint4 q0 = *(const uint4*)(lp + (size_t)c0 * 40);
            uint4 q1 = *(const uint4*)(lp + (size_t)c1 * 40);
            uint4 q2 = *(const uint4*)(lp + (size_t)c2 * 40);
            uint4 q3 = *(const uint4*)(lp + (size_t)c3 * 40);
            a0 += (blo(q0.x) + blo(q1.x)) + (blo(q2.x) + blo(q3.x));
            a1 += (bhi(q0.x) + bhi(q1.x)) + (bhi(q2.x) + bhi(q3.x));
            a2 += (blo(q0.y) + blo(q1.y)) + (blo(q2.y) + blo(q3.y));
            a3 += (bhi(q0.y) + bhi(q1.y)) + (bhi(q2.y) + bhi(q3.y));
            a4 += (blo(q0.z) + blo(q1.z)) + (blo(q2.z) + blo(q3.z));
            a5 += (bhi(q0.z) + bhi(q1.z)) + (bhi(q2.z) + bhi(q3.z));
            a6 += (blo(q0.w) + blo(q1.w)) + (blo(q2.w) + blo(q3.w));
            a7 += (bhi(q0.w) + bhi(q1.w)) + (bhi(q2.w) + bhi(q3.w));
        }
    }
    for (; j < d; ++j) {
        int c0 = col[s + j];
        if (act) {
            uint4 q0 = *(const uint4*)(lp + (size_t)c0 * 40);
            a0 += blo(q0.x); a1 += bhi(q0.x); a2 += blo(q0.y); a3 += bhi(q0.y);
            a4 += blo(q0.z); a5 += bhi(q0.z); a6 += blo(q0.w); a7 += bhi(q0.w);
        }
    }
    float w = 1.f / (float)(d > 0 ? d : 1);
    if (act) {
        float* op = out + (size_t)node * 40 + lane * 8;
        float4 r0 = *(const float4*)op;
        float4 r1 = *(const float4*)(op + 4);
        a0 = a0 * w + r0.x; a1 = a1 * w + r0.y; a2 = a2 * w + r0.z; a3 = a3 * w + r0.w;
        a4 = a4 * w + r1.x; a5 = a5 * w + r1.y; a6 = a6 * w + r1.z; a7 = a7 * w + r1.w;
    }
    float mx = act ? fmaxf(fmaxf(fmaxf(a0, a1), fmaxf(a2, a3)),
                           fmaxf(fmaxf(a4, a5), fmaxf(a6, a7))) : -3.4e38f;
#pragma unroll
    for (int off = 1; off < 8; off <<= 1) mx = fmaxf(mx, __shfl_xor(mx, off, 8));
    float ssum = act ? (expf(a0 - mx) + expf(a1 - mx) + expf(a2 - mx) + expf(a3 - mx) +
                        expf(a4 - mx) + expf(a5 - mx) + expf(a6 - mx) + expf(a7 - mx)) : 0.f;
#pragma unroll
    for (int off = 1; off < 8; off <<= 1) ssum += __shfl_xor(ssum, off, 8);
    float lg = mx + logf(ssum);
    if (act) {
        float* op = out + (size_t)node * 40 + lane * 8;
        float4 o0, o1;
        o0.x = a0 - lg; o0.y = a1 - lg; o0.z = a2 - lg; o0.w = a3 - lg;
        o1.x = a4 - lg; o1.y = a5 - lg; o1.z = a6 - lg; o1.w = a7 - lg;
        *(float4*)op = o0;
        *(float4*)(op + 4) = o1;
    }
}

// ---------------- launch ----------------
extern "C" void kernel_launch(void* const* d_in, const int* in_sizes, int n_in,
                              void* d_out, int out_size, void* d_ws, size_t ws_size,
                              hipStream_t stream) {
    const float* x   = (const float*)d_in[0];
    const int*   ei  = (const int*)d_in[1];
    const float* Wl1 = (const float*)d_in[2];
    const float* Wr1 = (const float*)d_in[3];
    const float* b1  = (const float*)d_in[4];
    const float* Wl2 = (const float*)d_in[5];
    const float* Wr2 = (const float*)d_in[6];
    const float* b2  = (const float*)d_in[7];
    const float* Wl3 = (const float*)d_in[8];
    const float* Wr3 = (const float*)d_in[9];
    const float* b3  = (const float*)d_in[10];
    float* out = (float*)d_out;

    const int N = in_sizes[0] / 64;
    const int E = in_sizes[1] / 2;
    const int NB = (N + BK_NODES - 1) / BK_NODES;
    const int* srcA = ei;
    const int* dstA = ei + E;

    char* ws = (char*)d_ws;
    size_t off = 0;
    auto alloc = [&](size_t bytes) {
        off = (off + 255) & ~(size_t)255;
        char* p = ws + off;
        off += bytes;
        return p;
    };
    int* cnts      = (int*)alloc((size_t)BBLK * NB_MAX * 4);
    int* lpre      = (int*)alloc((size_t)BBLK * NB_MAX * 4);
    int* bcount    = (int*)alloc((size_t)(NB_MAX + 1) * 4);
    int* bbase     = (int*)alloc((size_t)(NB_MAX + 1) * 4);
    int* binned    = (int*)alloc((size_t)E * 4);
    int* col       = (int*)alloc((size_t)E * 4);
    int* row_start = (int*)alloc((size_t)(N + 1) * 4);
    unsigned short* Xb  = (unsigned short*)alloc((size_t)N * 64 * 2);
    unsigned short* AGG = (unsigned short*)alloc((size_t)N * 64 * 2);
    unsigned short* Hb  = (unsigned short*)alloc((size_t)N * 64 * 2);
    unsigned short* Zb  = (unsigned short*)alloc((size_t)N * 40 * 2);
    unsigned short* Wb1 = (unsigned short*)alloc(8192 * 2);
    unsigned short* Wb2 = (unsigned short*)alloc(8192 * 2);
    unsigned short* Wb3 = (unsigned short*)alloc(6144 * 2);

    // build sorted CSR via dst-buckets, deterministic (no global atomics)
    prep_kernel<<<BBLK + 88 + 1024, 256, 0, stream>>>(dstA, cnts, E, NB, x, Xb, N * 64 / 8,
                                                      Wl1, Wr1, Wl2, Wr2, Wl3, Wr3, Wb1, Wb2, Wb3);
    colscan_kernel<<<NB, BBLK, 0, stream>>>(cnts, lpre, bcount);
    bscan_kernel<<<1, 1024, 0, stream>>>(bcount, bbase, NB, E);
    bin_kernel<<<BBLK, 512, 0, stream>>>(srcA, dstA, lpre, bbase, binned, E, NB);
    bsort_kernel<<<NB, 256, 0, stream>>>(binned, bbase, col, row_start, N);

    int gridA = (N + 31) / 32;
    int gridM = (N + 63) / 64;

    // layer 1: h1 -> Hb
    agg64_kernel<<<gridA, 256, 0, stream>>>(Xb, row_start, col, AGG, N);
    linmfma12_kernel<<<gridM, 256, 0, stream>>>(AGG, Xb, Wb1, b1, Hb, N);

    // layer 2 + layer-3 pre-transform fused: h2 stays in LDS
    agg64_kernel<<<gridA, 256, 0, stream>>>(Hb, row_start, col, AGG, N);
    lin23_kernel<<<gridM, 256, 0, stream>>>(AGG, Hb, Wb2, b2, Wb3, b3, Zb, out, N);

    // layer 3: agg(40) + self + log_softmax
    agg40lsm_kernel<<<gridA, 256, 0, stream>>>(Zb, row_start, col, out, N);
}